// Round 1
// baseline (378.072 us; speedup 1.0000x reference)
//
#include <hip/hip_runtime.h>
#include <math.h>

#define NR 4096
#define XD 256
#define ZD 128
#define HD 512
#define KG 260              // X_DIM + NUM_ACTIONS
#define NJR 8
#define JRANGE (NR / NJR)   // 512
#define INV_T 10.0f

// ---------------------------------------------------------------- concat
__global__ __launch_bounds__(256) void concat_kernel(const float* __restrict__ sp,
    const float* __restrict__ a1h, float* __restrict__ X2) {
  int row = blockIdx.x;
  int t = threadIdx.x;
  X2[(size_t)row * KG + t] = sp[(size_t)row * XD + t];
  if (t < 4) X2[(size_t)row * KG + XD + t] = a1h[(size_t)row * 4 + t];
}

// ---------------------------------------------------------------- GEMM
// C[M,N] = act(A[M,K] @ W[K,N] + b[N]); A,W,C row-major.
// BM=128, BN=64, BK=16; 256 threads; 8x4 microtile per thread.
template <bool RELU>
__global__ __launch_bounds__(256) void gemm_bias(const float* __restrict__ A,
    const float* __restrict__ W, const float* __restrict__ bias,
    float* __restrict__ C, int M, int N, int K) {
  const int BM = 128, BN = 64, BK = 16;
  __shared__ float As[BK][BM];   // transposed: As[k][m]
  __shared__ float Ws[BK][BN];   // Ws[k][n]
  int tid = threadIdx.x;
  int ty = tid >> 4;             // 0..15 -> 8 rows each
  int tx = tid & 15;             // 0..15 -> 4 cols each
  int bm = blockIdx.x * BM;
  int bn = blockIdx.y * BN;
  float acc[8][4] = {};

  for (int k0 = 0; k0 < K; k0 += BK) {
    // stage A tile (128x16) transposed: 512 float4, 2 per thread
#pragma unroll
    for (int su = 0; su < 2; ++su) {
      int idx = tid + su * 256;
      int row = idx >> 2;
      int c4 = (idx & 3) << 2;
      int k = k0 + c4;
      float4 v = make_float4(0.f, 0.f, 0.f, 0.f);
      if (k + 3 < K) {
        v = *reinterpret_cast<const float4*>(&A[(size_t)(bm + row) * K + k]);
      } else {
        float tmp[4] = {0.f, 0.f, 0.f, 0.f};
        for (int u = 0; u < 4; ++u)
          if (k + u < K) tmp[u] = A[(size_t)(bm + row) * K + k + u];
        v = make_float4(tmp[0], tmp[1], tmp[2], tmp[3]);
      }
      As[c4 + 0][row] = v.x;
      As[c4 + 1][row] = v.y;
      As[c4 + 2][row] = v.z;
      As[c4 + 3][row] = v.w;
    }
    // stage W tile (16x64): 256 float4, 1 per thread
    {
      int row = tid >> 4;
      int c4 = (tid & 15) << 2;
      float4 v = make_float4(0.f, 0.f, 0.f, 0.f);
      if (k0 + row < K)
        v = *reinterpret_cast<const float4*>(&W[(size_t)(k0 + row) * N + bn + c4]);
      *reinterpret_cast<float4*>(&Ws[row][c4]) = v;
    }
    __syncthreads();
#pragma unroll
    for (int kk = 0; kk < BK; ++kk) {
      float4 a0 = *reinterpret_cast<const float4*>(&As[kk][ty * 8]);
      float4 a1 = *reinterpret_cast<const float4*>(&As[kk][ty * 8 + 4]);
      float4 b = *reinterpret_cast<const float4*>(&Ws[kk][tx * 4]);
      float av[8] = {a0.x, a0.y, a0.z, a0.w, a1.x, a1.y, a1.z, a1.w};
      float bv[4] = {b.x, b.y, b.z, b.w};
#pragma unroll
      for (int i = 0; i < 8; ++i)
#pragma unroll
        for (int j = 0; j < 4; ++j) acc[i][j] += av[i] * bv[j];
    }
    __syncthreads();
  }
  // epilogue
#pragma unroll
  for (int i = 0; i < 8; ++i) {
    int row = bm + ty * 8 + i;
#pragma unroll
    for (int j = 0; j < 4; ++j) {
      int col = bn + tx * 4 + j;
      float v = acc[i][j] + bias[col];
      if (RELU) v = fmaxf(v, 0.f);
      C[(size_t)row * N + col] = v;
    }
  }
}

// ---------------------------------------------------------------- row norms of Zp
__global__ __launch_bounds__(256) void rowsq(const float* __restrict__ Zp,
                                             float* __restrict__ sqp) {
  int wave = threadIdx.x >> 6;
  int lane = threadIdx.x & 63;
  int row = blockIdx.x * 4 + wave;
  float v0 = Zp[(size_t)row * ZD + lane];
  float v1 = Zp[(size_t)row * ZD + 64 + lane];
  float sum = v0 * v0 + v1 * v1;
#pragma unroll
  for (int off = 32; off; off >>= 1) sum += __shfl_xor(sum, off, 64);
  if (lane == 0) sqp[row] = sum;
}

// ---------------------------------------------------------------- logits + online softmax partials
// grid: (NR/64) x NJR. Each block: rows [i0,i0+64), cols [jr*JRANGE, (jr+1)*JRANGE).
// Emits per-row partial (m, s) and (for the diag-owning j-range) l_ii.
__global__ __launch_bounds__(256) void logits_partial(
    const float* __restrict__ Z, const float* __restrict__ Zp,
    const float* __restrict__ sqp, float* __restrict__ wm,
    float* __restrict__ wsum, float* __restrict__ wdiag) {
  const int BI = 64, BJ = 64, BK = 16;
  __shared__ float As[BK][BI];
  __shared__ float Ws[BK][BJ];
  __shared__ float spj[BJ];
  int tid = threadIdx.x;
  int ty = tid >> 4;   // 0..15 -> 4 rows each
  int tx = tid & 15;   // 0..15 -> 4 cols each
  int i0 = blockIdx.x * BI;
  int jr = blockIdx.y;
  int j0base = jr * JRANGE;
  bool hasDiag = ((i0 / JRANGE) == jr);

  float m[4], s[4], dd[4];
#pragma unroll
  for (int i = 0; i < 4; ++i) { m[i] = -INFINITY; s[i] = 0.f; dd[i] = 0.f; }

  for (int jt = 0; jt < JRANGE / BJ; ++jt) {
    int j0 = j0base + jt * BJ;
    __syncthreads();                 // protect spj / tiles from previous iter readers
    if (tid < BJ) spj[tid] = sqp[j0 + tid];
    float acc[4][4] = {};
    for (int k0 = 0; k0 < ZD; k0 += BK) {
      // stage Z tile (64x16) and Zp tile (64x16), both transposed; 1 float4 each
      {
        int row = tid >> 2;
        int c4 = (tid & 3) << 2;
        float4 v = *reinterpret_cast<const float4*>(&Z[(size_t)(i0 + row) * ZD + k0 + c4]);
        As[c4 + 0][row] = v.x;
        As[c4 + 1][row] = v.y;
        As[c4 + 2][row] = v.z;
        As[c4 + 3][row] = v.w;
        float4 w = *reinterpret_cast<const float4*>(&Zp[(size_t)(j0 + row) * ZD + k0 + c4]);
        Ws[c4 + 0][row] = w.x;
        Ws[c4 + 1][row] = w.y;
        Ws[c4 + 2][row] = w.z;
        Ws[c4 + 3][row] = w.w;
      }
      __syncthreads();
#pragma unroll
      for (int kk = 0; kk < BK; ++kk) {
        float4 a = *reinterpret_cast<const float4*>(&As[kk][ty * 4]);
        float4 b = *reinterpret_cast<const float4*>(&Ws[kk][tx * 4]);
        float av[4] = {a.x, a.y, a.z, a.w};
        float bv[4] = {b.x, b.y, b.z, b.w};
#pragma unroll
        for (int i = 0; i < 4; ++i)
#pragma unroll
          for (int j = 0; j < 4; ++j) acc[i][j] += av[i] * bv[j];
      }
      __syncthreads();
    }
    // online softmax update over this 4x4 patch
#pragma unroll
    for (int i = 0; i < 4; ++i) {
      float l[4];
#pragma unroll
      for (int j = 0; j < 4; ++j)
        l[j] = (2.f * acc[i][j] - spj[tx * 4 + j]) * INV_T;
      float mt = fmaxf(fmaxf(l[0], l[1]), fmaxf(l[2], l[3]));
      float mn = fmaxf(m[i], mt);
      s[i] = s[i] * expf(m[i] - mn) + expf(l[0] - mn) + expf(l[1] - mn) +
             expf(l[2] - mn) + expf(l[3] - mn);
      m[i] = mn;
      if (j0 == i0 && tx == ty) dd[i] = l[i];   // diagonal element of row i0+ty*4+i
    }
  }
  // reduce (m,s) across the 16 tx-lanes sharing each row (contiguous in one wave)
#pragma unroll
  for (int i = 0; i < 4; ++i) {
    float mm = m[i], ss = s[i];
#pragma unroll
    for (int off = 1; off < 16; off <<= 1) {
      float mo = __shfl_xor(mm, off, 64);
      float so = __shfl_xor(ss, off, 64);
      float mn = fmaxf(mm, mo);
      ss = ss * expf(mm - mn) + so * expf(mo - mn);
      mm = mn;
    }
    int row = i0 + ty * 4 + i;
    if (tx == 0) {
      wm[(size_t)row * NJR + jr] = mm;
      wsum[(size_t)row * NJR + jr] = ss;
    }
    if (hasDiag && tx == ty) wdiag[row] = dd[i];
  }
}

// ---------------------------------------------------------------- final combine
__global__ __launch_bounds__(256) void finalize(const float* __restrict__ wm,
    const float* __restrict__ wsum, const float* __restrict__ wdiag,
    float* __restrict__ out) {
  int r = blockIdx.x * 256 + threadIdx.x;
  float mm = wm[(size_t)r * NJR];
  float ss = wsum[(size_t)r * NJR];
#pragma unroll
  for (int p = 1; p < NJR; ++p) {
    float mo = wm[(size_t)r * NJR + p];
    float so = wsum[(size_t)r * NJR + p];
    float mn = fmaxf(mm, mo);
    ss = ss * expf(mm - mn) + so * expf(mo - mn);
    mm = mn;
  }
  float loss_r = mm + logf(ss) - wdiag[r];
  // block-sum
  float v = loss_r;
#pragma unroll
  for (int off = 32; off; off >>= 1) v += __shfl_xor(v, off, 64);
  __shared__ float partial[4];
  if ((threadIdx.x & 63) == 0) partial[threadIdx.x >> 6] = v;
  __syncthreads();
  if (threadIdx.x == 0)
    atomicAdd(out, (partial[0] + partial[1] + partial[2] + partial[3]) * (1.0f / (float)NR));
}

// ---------------------------------------------------------------- launch
extern "C" void kernel_launch(void* const* d_in, const int* in_sizes, int n_in,
                              void* d_out, int out_size, void* d_ws, size_t ws_size,
                              hipStream_t stream) {
  const float* s   = (const float*)d_in[0];
  const float* sp  = (const float*)d_in[1];
  const float* a1h = (const float*)d_in[2];
  const float* pW0 = (const float*)d_in[3];
  const float* pb0 = (const float*)d_in[4];
  const float* pW1 = (const float*)d_in[5];
  const float* pb1 = (const float*)d_in[6];
  const float* pW2 = (const float*)d_in[7];
  const float* pb2 = (const float*)d_in[8];
  const float* gW0 = (const float*)d_in[9];
  const float* gb0 = (const float*)d_in[10];
  const float* gW1 = (const float*)d_in[11];
  const float* gb1 = (const float*)d_in[12];
  const float* gW2 = (const float*)d_in[13];
  const float* gb2 = (const float*)d_in[14];

  char* p = (char*)d_ws;
  float* X2  = (float*)p; p += (size_t)NR * KG * 4;
  float* H1  = (float*)p; p += (size_t)NR * HD * 4;
  float* H2  = (float*)p; p += (size_t)NR * HD * 4;
  float* Z   = (float*)p; p += (size_t)NR * ZD * 4;
  float* Zp  = (float*)p; p += (size_t)NR * ZD * 4;
  float* sqp = (float*)p; p += (size_t)NR * 4;
  float* wm  = (float*)p; p += (size_t)NR * NJR * 4;
  float* wsm = (float*)p; p += (size_t)NR * NJR * 4;
  float* wdg = (float*)p; p += (size_t)NR * 4;

  dim3 blk(256);
  concat_kernel<<<NR, blk, 0, stream>>>(sp, a1h, X2);
  // phi(s)
  gemm_bias<true ><<<dim3(NR / 128, HD / 64), blk, 0, stream>>>(s,  pW0, pb0, H1, NR, HD, XD);
  gemm_bias<true ><<<dim3(NR / 128, HD / 64), blk, 0, stream>>>(H1, pW1, pb1, H2, NR, HD, HD);
  gemm_bias<false><<<dim3(NR / 128, ZD / 64), blk, 0, stream>>>(H2, pW2, pb2, Z,  NR, ZD, HD);
  // g(concat(sp, a1h))
  gemm_bias<true ><<<dim3(NR / 128, HD / 64), blk, 0, stream>>>(X2, gW0, gb0, H1, NR, HD, KG);
  gemm_bias<true ><<<dim3(NR / 128, HD / 64), blk, 0, stream>>>(H1, gW1, gb1, H2, NR, HD, HD);
  gemm_bias<false><<<dim3(NR / 128, ZD / 64), blk, 0, stream>>>(H2, gW2, gb2, Zp, NR, ZD, HD);

  rowsq<<<NR / 4, blk, 0, stream>>>(Zp, sqp);
  hipMemsetAsync(d_out, 0, sizeof(float), stream);
  logits_partial<<<dim3(NR / 64, NJR), blk, 0, stream>>>(Z, Zp, sqp, wm, wsm, wdg);
  finalize<<<NR / 256, blk, 0, stream>>>(wm, wsm, wdg, (float*)d_out);
}

// Round 2
// 144.924 us; speedup vs baseline: 2.6088x; 2.6088x over previous
//
#include <hip/hip_runtime.h>
#include <hip/hip_bf16.h>
#include <math.h>

#define NR 4096
#define ZD 128
#define HD 512
#define NJR 8
#define INV_T 10.0f

typedef __attribute__((ext_vector_type(8))) short bf16x8;
typedef __attribute__((ext_vector_type(4))) short short4v;
typedef __attribute__((ext_vector_type(4))) float f32x4;

__device__ __forceinline__ unsigned short f2bf(float f) {
  union { float f; unsigned u; } v; v.f = f;
  unsigned r = v.u + 0x7fff + ((v.u >> 16) & 1);
  return (unsigned short)(r >> 16);
}
__device__ __forceinline__ float bf2f(unsigned short b) {
  union { unsigned u; float f; } v; v.u = ((unsigned)b) << 16;
  return v.f;
}

// ---------------------------------------------------------------- input casts
__global__ __launch_bounds__(256) void cast_in(const float* __restrict__ s,
    const float* __restrict__ sp, const float* __restrict__ a1h,
    unsigned short* __restrict__ Sb, unsigned short* __restrict__ SPb,
    int* __restrict__ aidx) {
  int row = blockIdx.x, t = threadIdx.x;
  Sb[(size_t)row * 256 + t] = f2bf(s[(size_t)row * 256 + t]);
  SPb[(size_t)row * 256 + t] = f2bf(sp[(size_t)row * 256 + t]);
  if (t < 4 && a1h[(size_t)row * 4 + t] > 0.5f) aidx[row] = t;
}

// ---------------------------------------------------------------- weight transpose+cast
// W [K][N] fp32 row-major -> Wt [N][K] bf16
__global__ __launch_bounds__(256) void tcast(const float* __restrict__ W,
    unsigned short* __restrict__ Wt, int K, int N) {
  __shared__ float t[32][33];
  int kb = blockIdx.x * 32, nb = blockIdx.y * 32;
  int tx = threadIdx.x & 31, ty = threadIdx.x >> 5;  // 32x8
#pragma unroll
  for (int r = 0; r < 32; r += 8) {
    int k = kb + ty + r, n = nb + tx;
    t[ty + r][tx] = (k < K && n < N) ? W[(size_t)k * N + n] : 0.f;
  }
  __syncthreads();
#pragma unroll
  for (int r = 0; r < 32; r += 8) {
    int n = nb + ty + r, k = kb + tx;
    if (n < N && k < K) Wt[(size_t)n * K + k] = f2bf(t[tx][ty + r]);
  }
}

// ---------------------------------------------------------------- MFMA fragment load from swizzled LDS tile
// tile layout: row-major [rows][64 bf16] = 128B rows, byte ^= (row&7)<<4
__device__ __forceinline__ bf16x8 ldfrag(const char* base, int row, int kbyte, int hi8) {
  int sw = (row & 7) << 4;
  int ro = row * 128;
  short4v lo = *(const short4v*)(base + ro + (((kbyte + hi8)) ^ sw));
  short4v hh = *(const short4v*)(base + ro + (((kbyte + hi8 + 32)) ^ sw));
  return __builtin_shufflevector(lo, hh, 0, 1, 2, 3, 4, 5, 6, 7);
}

// ---------------------------------------------------------------- GEMM (bf16 MFMA)
// C[M][N] = act(A[M][K] @ Wt[N][K]^T + bias);  A,Wt bf16; C bf16.
// BMODE 1: bias += gW0f[(256+aidx[row])*N + col]
template <bool RELU, int BMODE>
__global__ __launch_bounds__(256) void gemm_mfma(
    const unsigned short* __restrict__ A, const unsigned short* __restrict__ Wt,
    const float* __restrict__ bias, unsigned short* __restrict__ C,
    int M, int N, int K,
    const int* __restrict__ aidx, const float* __restrict__ gW0f) {
  __shared__ unsigned short As[64 * 64];
  __shared__ unsigned short Ws[64 * 64];
  const int tid = threadIdx.x;
  const int lane = tid & 63;
  const int wid = tid >> 6;
  const int wm = wid >> 1, wn = wid & 1;
  const int bm = blockIdx.x * 64, bn = blockIdx.y * 64;
  const int hi8 = (lane >> 4) * 8;
  const int l15 = lane & 15;

  f32x4 acc[2][2] = {};

  const int srow = tid >> 2;              // staging row 0..63
  const int schunk = (tid & 3) * 32;      // byte chunk within 128B row
  const int sw = (srow & 7) << 4;

  for (int k0 = 0; k0 < K; k0 += 64) {
    const unsigned short* ag = &A[(size_t)(bm + srow) * K + k0 + schunk / 2];
    const unsigned short* wg = &Wt[(size_t)(bn + srow) * K + k0 + schunk / 2];
    uint4 av0 = *(const uint4*)(ag);
    uint4 av1 = *(const uint4*)(ag + 8);
    uint4 wv0 = *(const uint4*)(wg);
    uint4 wv1 = *(const uint4*)(wg + 8);
    __syncthreads();   // previous tile fully consumed
    char* asb = (char*)As;
    char* wsb = (char*)Ws;
    *(uint4*)(asb + srow * 128 + ((schunk) ^ sw)) = av0;
    *(uint4*)(asb + srow * 128 + ((schunk + 16) ^ sw)) = av1;
    *(uint4*)(wsb + srow * 128 + ((schunk) ^ sw)) = wv0;
    *(uint4*)(wsb + srow * 128 + ((schunk + 16) ^ sw)) = wv1;
    __syncthreads();
#pragma unroll
    for (int ks = 0; ks < 2; ++ks) {
      bf16x8 af[2], bfr[2];
#pragma unroll
      for (int f = 0; f < 2; ++f) {
        af[f] = ldfrag((char*)As, wm * 32 + f * 16 + l15, ks * 64, hi8);
        bfr[f] = ldfrag((char*)Ws, wn * 32 + f * 16 + l15, ks * 64, hi8);
      }
#pragma unroll
      for (int fm = 0; fm < 2; ++fm)
#pragma unroll
        for (int fn = 0; fn < 2; ++fn)
          acc[fm][fn] = __builtin_amdgcn_mfma_f32_16x16x32_bf16(
              af[fm], bfr[fn], acc[fm][fn], 0, 0, 0);
    }
  }

  // epilogue: D layout col=lane&15, row=(lane>>4)*4+e
  const int row0 = bm + wm * 32;
  const int col0 = bn + wn * 32;
#pragma unroll
  for (int fm = 0; fm < 2; ++fm)
#pragma unroll
    for (int fn = 0; fn < 2; ++fn) {
      int col = col0 + fn * 16 + l15;
      float bb = bias[col];
      int rbase = row0 + fm * 16 + (lane >> 4) * 4;
#pragma unroll
      for (int e = 0; e < 4; ++e) {
        int row = rbase + e;
        float v = acc[fm][fn][e] + bb;
        if (BMODE == 1) v += gW0f[(size_t)(256 + aidx[row]) * N + col];
        if (RELU) v = fmaxf(v, 0.f);
        C[(size_t)row * N + col] = f2bf(v);
      }
    }
}

// ---------------------------------------------------------------- row norms of bf16 Zp
__global__ __launch_bounds__(256) void rowsq_bf(const unsigned short* __restrict__ Zpb,
                                                float* __restrict__ sqp) {
  int wave = threadIdx.x >> 6;
  int lane = threadIdx.x & 63;
  int row = blockIdx.x * 4 + wave;
  float v0 = bf2f(Zpb[(size_t)row * ZD + lane]);
  float v1 = bf2f(Zpb[(size_t)row * ZD + 64 + lane]);
  float sum = v0 * v0 + v1 * v1;
#pragma unroll
  for (int off = 32; off; off >>= 1) sum += __shfl_xor(sum, off, 64);
  if (lane == 0) sqp[row] = sum;
}

// ---------------------------------------------------------------- logits (MFMA) + online softmax partials
// grid: (NR/64) x NJR. Block: rows [i0,i0+64), cols [jr*512,(jr+1)*512).
__global__ __launch_bounds__(256) void logits_mfma(
    const unsigned short* __restrict__ Zb, const unsigned short* __restrict__ Zpb,
    const float* __restrict__ sqp, float* __restrict__ wm_,
    float* __restrict__ wsum, float* __restrict__ wdiag) {
  const int tid = threadIdx.x, lane = tid & 63, w = tid >> 6;
  const int i0 = blockIdx.x * 64;
  const int jr = blockIdx.y;
  const int row16 = i0 + w * 16;          // wave's 16-row strip
  const int l15 = lane & 15;
  const int hi4 = (lane >> 4) * 4;        // element offset within row

  // A fragments: Z strip, 4 k-steps of 32, held in registers for whole kernel
  bf16x8 afr[4];
  {
    const unsigned short* zr = &Zb[(size_t)(row16 + l15) * ZD];
#pragma unroll
    for (int ks = 0; ks < 4; ++ks) {
      short4v lo = *(const short4v*)(zr + ks * 32 + hi4);
      short4v hh = *(const short4v*)(zr + ks * 32 + hi4 + 16);
      afr[ks] = __builtin_shufflevector(lo, hh, 0, 1, 2, 3, 4, 5, 6, 7);
    }
  }

  float m[4], s[4], dd[4];
#pragma unroll
  for (int e = 0; e < 4; ++e) { m[e] = -INFINITY; s[e] = 0.f; dd[e] = 0.f; }

  const int jbase = jr * 512;
  for (int jt = 0; jt < 8; ++jt) {
    int j0 = jbase + jt * 64;
    f32x4 acc[4] = {};
#pragma unroll
    for (int fn = 0; fn < 4; ++fn) {
      const unsigned short* pr = &Zpb[(size_t)(j0 + fn * 16 + l15) * ZD];
#pragma unroll
      for (int ks = 0; ks < 4; ++ks) {
        short4v lo = *(const short4v*)(pr + ks * 32 + hi4);
        short4v hh = *(const short4v*)(pr + ks * 32 + hi4 + 16);
        bf16x8 bfr = __builtin_shufflevector(lo, hh, 0, 1, 2, 3, 4, 5, 6, 7);
        acc[fn] = __builtin_amdgcn_mfma_f32_16x16x32_bf16(afr[ks], bfr, acc[fn], 0, 0, 0);
      }
    }
    float spv[4];
#pragma unroll
    for (int fn = 0; fn < 4; ++fn) spv[fn] = sqp[j0 + fn * 16 + l15];
#pragma unroll
    for (int e = 0; e < 4; ++e) {
      int grow = row16 + hi4 + e;
      float l[4];
#pragma unroll
      for (int fn = 0; fn < 4; ++fn) {
        int col = j0 + fn * 16 + l15;
        l[fn] = (2.f * acc[fn][e] - spv[fn]) * INV_T;
        if (col == grow) dd[e] = l[fn];
      }
      float mt = fmaxf(fmaxf(l[0], l[1]), fmaxf(l[2], l[3]));
      float mn = fmaxf(m[e], mt);
      float sc = __expf(m[e] - mn);
      s[e] = s[e] * sc + __expf(l[0] - mn) + __expf(l[1] - mn) +
             __expf(l[2] - mn) + __expf(l[3] - mn);
      m[e] = mn;
    }
  }
  // reduce (m,s) across the 16 lanes of each hi-group
#pragma unroll
  for (int e = 0; e < 4; ++e) {
    float mm = m[e], ss = s[e];
#pragma unroll
    for (int off = 1; off < 16; off <<= 1) {
      float mo = __shfl_xor(mm, off, 64);
      float so = __shfl_xor(ss, off, 64);
      float mn = fmaxf(mm, mo);
      ss = ss * __expf(mm - mn) + so * __expf(mo - mn);
      mm = mn;
    }
    int grow = row16 + hi4 + e;
    if (l15 == 0) {
      wm_[(size_t)grow * NJR + jr] = mm;
      wsum[(size_t)grow * NJR + jr] = ss;
    }
    if ((grow >> 9) == jr && l15 == (grow & 15)) wdiag[grow] = dd[e];
  }
}

// ---------------------------------------------------------------- final combine
__global__ __launch_bounds__(256) void finalize(const float* __restrict__ wm,
    const float* __restrict__ wsum, const float* __restrict__ wdiag,
    float* __restrict__ out) {
  int r = blockIdx.x * 256 + threadIdx.x;
  float mm = wm[(size_t)r * NJR];
  float ss = wsum[(size_t)r * NJR];
#pragma unroll
  for (int p = 1; p < NJR; ++p) {
    float mo = wm[(size_t)r * NJR + p];
    float so = wsum[(size_t)r * NJR + p];
    float mn = fmaxf(mm, mo);
    ss = ss * expf(mm - mn) + so * expf(mo - mn);
    mm = mn;
  }
  float loss_r = mm + logf(ss) - wdiag[r];
  float v = loss_r;
#pragma unroll
  for (int off = 32; off; off >>= 1) v += __shfl_xor(v, off, 64);
  __shared__ float partial[4];
  if ((threadIdx.x & 63) == 0) partial[threadIdx.x >> 6] = v;
  __syncthreads();
  if (threadIdx.x == 0)
    atomicAdd(out, (partial[0] + partial[1] + partial[2] + partial[3]) * (1.0f / (float)NR));
}

// ---------------------------------------------------------------- launch
extern "C" void kernel_launch(void* const* d_in, const int* in_sizes, int n_in,
                              void* d_out, int out_size, void* d_ws, size_t ws_size,
                              hipStream_t stream) {
  const float* s   = (const float*)d_in[0];
  const float* sp  = (const float*)d_in[1];
  const float* a1h = (const float*)d_in[2];
  const float* pW0 = (const float*)d_in[3];
  const float* pb0 = (const float*)d_in[4];
  const float* pW1 = (const float*)d_in[5];
  const float* pb1 = (const float*)d_in[6];
  const float* pW2 = (const float*)d_in[7];
  const float* pb2 = (const float*)d_in[8];
  const float* gW0 = (const float*)d_in[9];
  const float* gb0 = (const float*)d_in[10];
  const float* gW1 = (const float*)d_in[11];
  const float* gb1 = (const float*)d_in[12];
  const float* gW2 = (const float*)d_in[13];
  const float* gb2 = (const float*)d_in[14];

  char* p = (char*)d_ws;
  unsigned short* Sb   = (unsigned short*)p; p += (size_t)NR * 256 * 2;
  unsigned short* SPb  = (unsigned short*)p; p += (size_t)NR * 256 * 2;
  unsigned short* H1b  = (unsigned short*)p; p += (size_t)NR * HD * 2;
  unsigned short* H2b  = (unsigned short*)p; p += (size_t)NR * HD * 2;
  unsigned short* Zb   = (unsigned short*)p; p += (size_t)NR * ZD * 2;
  unsigned short* Zpb  = (unsigned short*)p; p += (size_t)NR * ZD * 2;
  unsigned short* pW0t = (unsigned short*)p; p += (size_t)256 * 512 * 2;
  unsigned short* pW1t = (unsigned short*)p; p += (size_t)512 * 512 * 2;
  unsigned short* pW2t = (unsigned short*)p; p += (size_t)512 * 128 * 2;
  unsigned short* gW0t = (unsigned short*)p; p += (size_t)256 * 512 * 2;
  unsigned short* gW1t = (unsigned short*)p; p += (size_t)512 * 512 * 2;
  unsigned short* gW2t = (unsigned short*)p; p += (size_t)512 * 128 * 2;
  float* sqp  = (float*)p; p += (size_t)NR * 4;
  float* wm   = (float*)p; p += (size_t)NR * NJR * 4;
  float* wsm  = (float*)p; p += (size_t)NR * NJR * 4;
  float* wdg  = (float*)p; p += (size_t)NR * 4;
  int*   aidx = (int*)p;  p += (size_t)NR * 4;

  dim3 blk(256);
  cast_in<<<NR, blk, 0, stream>>>(s, sp, a1h, Sb, SPb, aidx);
  tcast<<<dim3(8, 16), blk, 0, stream>>>(pW0, pW0t, 256, 512);
  tcast<<<dim3(16, 16), blk, 0, stream>>>(pW1, pW1t, 512, 512);
  tcast<<<dim3(16, 4), blk, 0, stream>>>(pW2, pW2t, 512, 128);
  tcast<<<dim3(8, 16), blk, 0, stream>>>(gW0, gW0t, 256, 512);   // first 256 rows only
  tcast<<<dim3(16, 16), blk, 0, stream>>>(gW1, gW1t, 512, 512);
  tcast<<<dim3(16, 4), blk, 0, stream>>>(gW2, gW2t, 512, 128);

  gemm_mfma<true, 0><<<dim3(64, 8), blk, 0, stream>>>(Sb,  pW0t, pb0, H1b, NR, 512, 256, nullptr, nullptr);
  gemm_mfma<true, 0><<<dim3(64, 8), blk, 0, stream>>>(H1b, pW1t, pb1, H2b, NR, 512, 512, nullptr, nullptr);
  gemm_mfma<false, 0><<<dim3(64, 2), blk, 0, stream>>>(H2b, pW2t, pb2, Zb, NR, 128, 512, nullptr, nullptr);
  gemm_mfma<true, 1><<<dim3(64, 8), blk, 0, stream>>>(SPb, gW0t, gb0, H1b, NR, 512, 256, aidx, gW0);
  gemm_mfma<true, 0><<<dim3(64, 8), blk, 0, stream>>>(H1b, gW1t, gb1, H2b, NR, 512, 512, nullptr, nullptr);
  gemm_mfma<false, 0><<<dim3(64, 2), blk, 0, stream>>>(H2b, gW2t, gb2, Zpb, NR, 128, 512, nullptr, nullptr);

  rowsq_bf<<<NR / 4, blk, 0, stream>>>(Zpb, sqp);
  hipMemsetAsync(d_out, 0, sizeof(float), stream);
  logits_mfma<<<dim3(NR / 64, NJR), blk, 0, stream>>>(Zb, Zpb, sqp, wm, wsm, wdg);
  finalize<<<NR / 256, blk, 0, stream>>>(wm, wsm, wdg, (float*)d_out);
}

// Round 3
// 66.212 us; speedup vs baseline: 5.7100x; 2.1888x over previous
//
#include <hip/hip_runtime.h>
#include <math.h>

#define NR 4096
#define ZD 128
#define HD 512
#define NJR 32
#define JC 128              // cols per logits block (2 tiles of 64)
#define INV_T 10.0f

typedef __attribute__((ext_vector_type(8))) short bf16x8;
typedef __attribute__((ext_vector_type(4))) short short4v;
typedef __attribute__((ext_vector_type(4))) float f32x4;

__device__ __forceinline__ unsigned short f2bf(float f) {
  union { float f; unsigned u; } v; v.f = f;
  unsigned r = v.u + 0x7fff + ((v.u >> 16) & 1);
  return (unsigned short)(r >> 16);
}
__device__ __forceinline__ float bf2f(unsigned short b) {
  union { unsigned u; float f; } v; v.u = ((unsigned)b) << 16;
  return v.f;
}

// ---------------- fragment-major LDS tile (64 rows x KS*32 cols bf16) ----------------
// frag (rf=row/16, ks) for lane (hi,l15) = row rf*16+l15, elems ks*32+hi*4+{0..3, 16..19}
// LDS: linear = (rf*KS+ks)*1024 + lane*16 + sub;  addr = linear ^ (((linear>>8)&7)<<4)
__device__ __forceinline__ int swz(int lin) { return lin ^ (((lin >> 8) & 7) << 4); }

template <int KS>
__device__ __forceinline__ void stage_chunk(char* lds, int ch, uint4 v) {
  int j   = ch / (KS * 4);          // tile row
  int cq  = ch - j * (KS * 4);
  int c0  = cq * 8;                 // element offset in row
  int ks  = c0 >> 5;
  int o   = c0 & 31;
  int hiP = (o & 8) ? 2 : 0;
  int hh  = (o & 16) ? 8 : 0;
  int slot = (j >> 4) * KS + ks;
  int l15 = j & 15;
  int linA = slot * 1024 + (hiP * 16 + l15) * 16 + hh;   // elems 0-3 -> lane hiP
  int linB = linA + 256;                                  // elems 4-7 -> lane hiP+1
  *(uint2*)(lds + swz(linA)) = make_uint2(v.x, v.y);
  *(uint2*)(lds + swz(linB)) = make_uint2(v.z, v.w);
}

template <int KS>
__device__ __forceinline__ bf16x8 ldfrag(const char* lds, int rf, int ks, int lane) {
  int lin = (rf * KS + ks) * 1024 + lane * 16;
  return *(const bf16x8*)(lds + swz(lin));
}

// ---------------------------------------------------------------- input casts
__global__ __launch_bounds__(256) void cast_in(const float* __restrict__ s,
    const float* __restrict__ sp, const float* __restrict__ a1h,
    unsigned short* __restrict__ Sb, unsigned short* __restrict__ SPb,
    int* __restrict__ aidx) {
  int row = blockIdx.x, t = threadIdx.x;
  Sb[(size_t)row * 256 + t] = f2bf(s[(size_t)row * 256 + t]);
  SPb[(size_t)row * 256 + t] = f2bf(sp[(size_t)row * 256 + t]);
  if (t < 4 && a1h[(size_t)row * 4 + t] > 0.5f) aidx[row] = t;
}

// ---------------------------------------------------------------- all weight transposes
__global__ __launch_bounds__(256) void tcast_all(
    const float* __restrict__ pW0, unsigned short* __restrict__ pW0t,
    const float* __restrict__ pW1, unsigned short* __restrict__ pW1t,
    const float* __restrict__ pW2, unsigned short* __restrict__ pW2t,
    const float* __restrict__ gW0, unsigned short* __restrict__ gW0t,
    const float* __restrict__ gW1, unsigned short* __restrict__ gW1t,
    const float* __restrict__ gW2, unsigned short* __restrict__ gW2t) {
  int b = blockIdx.x;
  const float* W; unsigned short* Wt; int K, N, t;
  if (b < 128)      { W = pW0; Wt = pW0t; K = 256; N = 512; t = b; }
  else if (b < 384) { W = pW1; Wt = pW1t; K = 512; N = 512; t = b - 128; }
  else if (b < 448) { W = pW2; Wt = pW2t; K = 512; N = 128; t = b - 384; }
  else if (b < 576) { W = gW0; Wt = gW0t; K = 256; N = 512; t = b - 448; }
  else if (b < 832) { W = gW1; Wt = gW1t; K = 512; N = 512; t = b - 576; }
  else              { W = gW2; Wt = gW2t; K = 512; N = 128; t = b - 832; }
  int nk = K >> 5;
  int kb = (t % nk) * 32, nb = (t / nk) * 32;
  __shared__ float tile[32][33];
  int tx = threadIdx.x & 31, ty = threadIdx.x >> 5;
#pragma unroll
  for (int r = 0; r < 32; r += 8)
    tile[ty + r][tx] = W[(size_t)(kb + ty + r) * N + nb + tx];
  __syncthreads();
#pragma unroll
  for (int r = 0; r < 32; r += 8)
    Wt[(size_t)(nb + ty + r) * K + kb + tx] = f2bf(tile[tx][ty + r]);
}

// ---------------------------------------------------------------- paired GEMM (bf16 MFMA)
// z=0: C0 = act(A0 @ W0^T + b0);  z=1: C1 = act(A1 @ W1^T + b1 [+ gW0 action row])
template <bool RELU>
__global__ __launch_bounds__(256) void gemm_pair(
    const unsigned short* __restrict__ A0, const unsigned short* __restrict__ A1,
    const unsigned short* __restrict__ W0, const unsigned short* __restrict__ W1,
    const float* __restrict__ b0, const float* __restrict__ b1,
    unsigned short* __restrict__ C0, unsigned short* __restrict__ C1,
    int N, int K, int bm1flag,
    const int* __restrict__ aidx, const float* __restrict__ gW0f) {
  __shared__ char lds[16384];
  char* As = lds;
  char* Ws = lds + 8192;
  const int tid = threadIdx.x, lane = tid & 63, wid = tid >> 6;
  const int wm = wid >> 1, wn = wid & 1;
  const int bm = blockIdx.x * 64, bn = blockIdx.y * 64;
  const int z = blockIdx.z;
  const unsigned short* A = z ? A1 : A0;
  const unsigned short* W = z ? W1 : W0;
  const float* bias = z ? b1 : b0;
  unsigned short* C = z ? C1 : C0;
  const bool gbias = (z == 1) && bm1flag;

  // staging coords: chunk ch = u*256+tid; row j = ch>>3 (8 chunks/row), c0 = (ch&7)*8
  const int jc = tid >> 3, cc = (tid & 7) * 8;
  uint4 ra0, ra1, rw0, rw1;
  ra0 = *(const uint4*)&A[(size_t)(bm + jc) * K + cc];
  ra1 = *(const uint4*)&A[(size_t)(bm + 32 + jc) * K + cc];
  rw0 = *(const uint4*)&W[(size_t)(bn + jc) * K + cc];
  rw1 = *(const uint4*)&W[(size_t)(bn + 32 + jc) * K + cc];

  f32x4 acc[2][2] = {};
  for (int k0 = 0; k0 < K; k0 += 64) {
    __syncthreads();                       // previous tile fully consumed
    stage_chunk<2>(As, tid, ra0);
    stage_chunk<2>(As, tid + 256, ra1);
    stage_chunk<2>(Ws, tid, rw0);
    stage_chunk<2>(Ws, tid + 256, rw1);
    if (k0 + 64 < K) {                     // prefetch next tile (overlaps MFMA)
      int kn = k0 + 64;
      ra0 = *(const uint4*)&A[(size_t)(bm + jc) * K + kn + cc];
      ra1 = *(const uint4*)&A[(size_t)(bm + 32 + jc) * K + kn + cc];
      rw0 = *(const uint4*)&W[(size_t)(bn + jc) * K + kn + cc];
      rw1 = *(const uint4*)&W[(size_t)(bn + 32 + jc) * K + kn + cc];
    }
    __syncthreads();
#pragma unroll
    for (int ks = 0; ks < 2; ++ks) {
      bf16x8 af[2], bfv[2];
#pragma unroll
      for (int f = 0; f < 2; ++f) {
        af[f]  = ldfrag<2>(As, wm * 2 + f, ks, lane);
        bfv[f] = ldfrag<2>(Ws, wn * 2 + f, ks, lane);
      }
#pragma unroll
      for (int fm = 0; fm < 2; ++fm)
#pragma unroll
        for (int fn = 0; fn < 2; ++fn)
          acc[fm][fn] = __builtin_amdgcn_mfma_f32_16x16x32_bf16(
              af[fm], bfv[fn], acc[fm][fn], 0, 0, 0);
    }
  }

  const int l15 = lane & 15, hi = lane >> 4;
  const int row0 = bm + wm * 32, col0 = bn + wn * 32;
#pragma unroll
  for (int fm = 0; fm < 2; ++fm)
#pragma unroll
    for (int fn = 0; fn < 2; ++fn) {
      int col = col0 + fn * 16 + l15;
      float bb = bias[col];
      int rbase = row0 + fm * 16 + hi * 4;
#pragma unroll
      for (int e = 0; e < 4; ++e) {
        int row = rbase + e;
        float v = acc[fm][fn][e] + bb;
        if (gbias) v += gW0f[(size_t)(256 + aidx[row]) * N + col];
        if (RELU) v = fmaxf(v, 0.f);
        C[(size_t)row * N + col] = f2bf(v);
      }
    }
}

// ---------------------------------------------------------------- row norms of bf16 Zp
__global__ __launch_bounds__(256) void rowsq_bf(const unsigned short* __restrict__ Zpb,
                                                float* __restrict__ sqp) {
  int wave = threadIdx.x >> 6;
  int lane = threadIdx.x & 63;
  int row = blockIdx.x * 4 + wave;
  float v0 = bf2f(Zpb[(size_t)row * ZD + lane]);
  float v1 = bf2f(Zpb[(size_t)row * ZD + 64 + lane]);
  float sum = v0 * v0 + v1 * v1;
#pragma unroll
  for (int off = 32; off; off >>= 1) sum += __shfl_xor(sum, off, 64);
  if (lane == 0) sqp[row] = sum;
}

// ---------------------------------------------------------------- logits + online softmax
// grid: (NR/64) x NJR. Block: 64 rows x 128 cols (2 j-tiles), LDS-staged Zp.
__global__ __launch_bounds__(256) void logits_mfma(
    const unsigned short* __restrict__ Zb, const unsigned short* __restrict__ Zpb,
    const float* __restrict__ sqp, float* __restrict__ wm_,
    float* __restrict__ wsum, float* __restrict__ wdiag) {
  __shared__ char Ps[16384];
  const int tid = threadIdx.x, lane = tid & 63, w = tid >> 6;
  const int l15 = lane & 15, hi4 = (lane >> 4) * 4;
  const int i0 = blockIdx.x * 64, jr = blockIdx.y;
  const int row16 = i0 + w * 16;
  const int jbase = jr * JC;

  // A fragments: wave's 16-row Z strip in registers
  bf16x8 afr[4];
  {
    const unsigned short* zr = &Zb[(size_t)(row16 + l15) * ZD];
#pragma unroll
    for (int ks = 0; ks < 4; ++ks) {
      short4v lo = *(const short4v*)(zr + ks * 32 + hi4);
      short4v hh = *(const short4v*)(zr + ks * 32 + hi4 + 16);
      afr[ks] = __builtin_shufflevector(lo, hh, 0, 1, 2, 3, 4, 5, 6, 7);
    }
  }

  float m[4], s[4], dd[4];
#pragma unroll
  for (int e = 0; e < 4; ++e) { m[e] = -INFINITY; s[e] = 0.f; dd[e] = 0.f; }

  const int jloc = tid >> 4, cloc = (tid & 15) * 8;   // 16 chunks per 256B row
  uint4 rv[4];

#define LOADP(jt) { \
    const unsigned short* src = &Zpb[(size_t)(jbase + (jt) * 64) * ZD]; \
    rv[0] = *(const uint4*)&src[(size_t)(jloc +  0) * ZD + cloc]; \
    rv[1] = *(const uint4*)&src[(size_t)(jloc + 16) * ZD + cloc]; \
    rv[2] = *(const uint4*)&src[(size_t)(jloc + 32) * ZD + cloc]; \
    rv[3] = *(const uint4*)&src[(size_t)(jloc + 48) * ZD + cloc]; }

#define STAGEP() { \
    stage_chunk<4>(Ps, tid, rv[0]); \
    stage_chunk<4>(Ps, tid + 256, rv[1]); \
    stage_chunk<4>(Ps, tid + 512, rv[2]); \
    stage_chunk<4>(Ps, tid + 768, rv[3]); }

  auto compute = [&](int jt) {
    const int j0 = jbase + jt * 64;
    f32x4 acc[4] = {};
#pragma unroll
    for (int ks = 0; ks < 4; ++ks) {
      bf16x8 bfv[4];
#pragma unroll
      for (int fn = 0; fn < 4; ++fn) bfv[fn] = ldfrag<4>(Ps, fn, ks, lane);
#pragma unroll
      for (int fn = 0; fn < 4; ++fn)
        acc[fn] = __builtin_amdgcn_mfma_f32_16x16x32_bf16(afr[ks], bfv[fn], acc[fn], 0, 0, 0);
    }
    float spv[4];
#pragma unroll
    for (int fn = 0; fn < 4; ++fn) spv[fn] = sqp[j0 + fn * 16 + l15];
#pragma unroll
    for (int e = 0; e < 4; ++e) {
      int grow = row16 + hi4 + e;
      float l[4];
#pragma unroll
      for (int fn = 0; fn < 4; ++fn) {
        int col = j0 + fn * 16 + l15;
        l[fn] = (2.f * acc[fn][e] - spv[fn]) * INV_T;
        if (col == grow) dd[e] = l[fn];
      }
      float mt = fmaxf(fmaxf(l[0], l[1]), fmaxf(l[2], l[3]));
      float mn = fmaxf(m[e], mt);
      s[e] = s[e] * __expf(m[e] - mn) + __expf(l[0] - mn) + __expf(l[1] - mn) +
             __expf(l[2] - mn) + __expf(l[3] - mn);
      m[e] = mn;
    }
  };

  LOADP(0);
  STAGEP();
  LOADP(1);          // prefetch tile 1 (in flight during compute(0))
  __syncthreads();
  compute(0);
  __syncthreads();
  STAGEP();
  __syncthreads();
  compute(1);

#pragma unroll
  for (int e = 0; e < 4; ++e) {
    float mm = m[e], ss = s[e];
#pragma unroll
    for (int off = 1; off < 16; off <<= 1) {
      float mo = __shfl_xor(mm, off, 64);
      float so = __shfl_xor(ss, off, 64);
      float mn = fmaxf(mm, mo);
      ss = ss * __expf(mm - mn) + so * __expf(mo - mn);
      mm = mn;
    }
    int grow = row16 + hi4 + e;
    if (l15 == 0) {
      wm_[(size_t)jr * NR + grow] = mm;    // [NJR][NR] for coalesced finalize
      wsum[(size_t)jr * NR + grow] = ss;
    }
    if ((grow >> 7) == jr && l15 == (grow & 15)) wdiag[grow] = dd[e];
  }
#undef LOADP
#undef STAGEP
}

// ---------------------------------------------------------------- final combine
__global__ __launch_bounds__(256) void finalize(const float* __restrict__ wm,
    const float* __restrict__ wsum, const float* __restrict__ wdiag,
    float* __restrict__ out) {
  int r = blockIdx.x * 256 + threadIdx.x;
  float mm = wm[r];
  float ss = wsum[r];
#pragma unroll
  for (int p = 1; p < NJR; ++p) {
    float mo = wm[(size_t)p * NR + r];
    float so = wsum[(size_t)p * NR + r];
    float mn = fmaxf(mm, mo);
    ss = ss * __expf(mm - mn) + so * __expf(mo - mn);
    mm = mn;
  }
  float loss_r = mm + logf(ss) - wdiag[r];
  float v = loss_r;
#pragma unroll
  for (int off = 32; off; off >>= 1) v += __shfl_xor(v, off, 64);
  __shared__ float partial[4];
  if ((threadIdx.x & 63) == 0) partial[threadIdx.x >> 6] = v;
  __syncthreads();
  if (threadIdx.x == 0)
    atomicAdd(out, (partial[0] + partial[1] + partial[2] + partial[3]) * (1.0f / (float)NR));
}

// ---------------------------------------------------------------- launch
extern "C" void kernel_launch(void* const* d_in, const int* in_sizes, int n_in,
                              void* d_out, int out_size, void* d_ws, size_t ws_size,
                              hipStream_t stream) {
  const float* s   = (const float*)d_in[0];
  const float* sp  = (const float*)d_in[1];
  const float* a1h = (const float*)d_in[2];
  const float* pW0 = (const float*)d_in[3];
  const float* pb0 = (const float*)d_in[4];
  const float* pW1 = (const float*)d_in[5];
  const float* pb1 = (const float*)d_in[6];
  const float* pW2 = (const float*)d_in[7];
  const float* pb2 = (const float*)d_in[8];
  const float* gW0 = (const float*)d_in[9];
  const float* gb0 = (const float*)d_in[10];
  const float* gW1 = (const float*)d_in[11];
  const float* gb1 = (const float*)d_in[12];
  const float* gW2 = (const float*)d_in[13];
  const float* gb2 = (const float*)d_in[14];

  char* p = (char*)d_ws;
  unsigned short* Sb   = (unsigned short*)p; p += (size_t)NR * 256 * 2;
  unsigned short* SPb  = (unsigned short*)p; p += (size_t)NR * 256 * 2;
  unsigned short* H1   = (unsigned short*)p; p += (size_t)2 * NR * HD * 2;  // [2][NR][HD]
  unsigned short* H2   = (unsigned short*)p; p += (size_t)2 * NR * HD * 2;
  unsigned short* Zall = (unsigned short*)p; p += (size_t)2 * NR * ZD * 2;  // [2][NR][ZD]
  unsigned short* pW0t = (unsigned short*)p; p += (size_t)256 * 512 * 2;
  unsigned short* pW1t = (unsigned short*)p; p += (size_t)512 * 512 * 2;
  unsigned short* pW2t = (unsigned short*)p; p += (size_t)512 * 128 * 2;
  unsigned short* gW0t = (unsigned short*)p; p += (size_t)256 * 512 * 2;
  unsigned short* gW1t = (unsigned short*)p; p += (size_t)512 * 512 * 2;
  unsigned short* gW2t = (unsigned short*)p; p += (size_t)512 * 128 * 2;
  float* sqp  = (float*)p; p += (size_t)NR * 4;
  float* wm   = (float*)p; p += (size_t)NJR * NR * 4;
  float* wsm  = (float*)p; p += (size_t)NJR * NR * 4;
  float* wdg  = (float*)p; p += (size_t)NR * 4;
  int*   aidx = (int*)p;  p += (size_t)NR * 4;

  unsigned short* H1g = H1 + (size_t)NR * HD;
  unsigned short* H2g = H2 + (size_t)NR * HD;
  unsigned short* Zb  = Zall;
  unsigned short* Zpb = Zall + (size_t)NR * ZD;

  dim3 blk(256);
  cast_in<<<NR, blk, 0, stream>>>(s, sp, a1h, Sb, SPb, aidx);
  tcast_all<<<896, blk, 0, stream>>>(pW0, pW0t, pW1, pW1t, pW2, pW2t,
                                     gW0, gW0t, gW1, gW1t, gW2, gW2t);

  gemm_pair<true><<<dim3(64, 8, 2), blk, 0, stream>>>(
      Sb, SPb, pW0t, gW0t, pb0, gb0, H1, H1g, 512, 256, 1, aidx, gW0);
  gemm_pair<true><<<dim3(64, 8, 2), blk, 0, stream>>>(
      H1, H1g, pW1t, gW1t, pb1, gb1, H2, H2g, 512, 512, 0, nullptr, nullptr);
  gemm_pair<false><<<dim3(64, 2, 2), blk, 0, stream>>>(
      H2, H2g, pW2t, gW2t, pb2, gb2, Zb, Zpb, 128, 512, 0, nullptr, nullptr);

  rowsq_bf<<<NR / 4, blk, 0, stream>>>(Zpb, sqp);
  hipMemsetAsync(d_out, 0, sizeof(float), stream);
  logits_mfma<<<dim3(NR / 64, NJR), blk, 0, stream>>>(Zb, Zpb, sqp, wm, wsm, wdg);
  finalize<<<NR / 256, blk, 0, stream>>>(wm, wsm, wdg, (float*)d_out);
}

// Round 4
// 65.631 us; speedup vs baseline: 5.7606x; 1.0089x over previous
//
#include <hip/hip_runtime.h>
#include <math.h>

#define NR 4096
#define ZD 128
#define HD 512
#define NJR 32
#define JC 128              // cols per logits block (2 tiles of 64)
#define INV_T 10.0f

typedef __attribute__((ext_vector_type(8))) short bf16x8;
typedef __attribute__((ext_vector_type(4))) short short4v;
typedef __attribute__((ext_vector_type(4))) float f32x4;

__device__ __forceinline__ unsigned short f2bf(float f) {
  union { float f; unsigned u; } v; v.f = f;
  unsigned r = v.u + 0x7fff + ((v.u >> 16) & 1);
  return (unsigned short)(r >> 16);
}
__device__ __forceinline__ float bf2f(unsigned short b) {
  union { unsigned u; float f; } v; v.u = ((unsigned)b) << 16;
  return v.f;
}

// ---------------- fragment-major LDS tile (rows x KS*32 cols bf16) ----------------
// frag (rf=row/16, ks) for lane (hi,l15) = row rf*16+l15, elems ks*32+hi*4+{0..3,16..19}
// LDS: linear = (rf*KS+ks)*1024 + lane*16 + sub;  addr = linear ^ (((linear>>8)&7)<<4)
__device__ __forceinline__ int swz(int lin) { return lin ^ (((lin >> 8) & 7) << 4); }

template <int KS>
__device__ __forceinline__ void stage_chunk(char* lds, int ch, uint4 v) {
  int j   = ch / (KS * 4);          // tile row
  int cq  = ch - j * (KS * 4);
  int c0  = cq * 8;                 // element offset in row
  int ks  = c0 >> 5;
  int o   = c0 & 31;
  int hiP = (o & 8) ? 2 : 0;
  int hh  = (o & 16) ? 8 : 0;
  int slot = (j >> 4) * KS + ks;
  int l15 = j & 15;
  int linA = slot * 1024 + (hiP * 16 + l15) * 16 + hh;   // elems 0-3 -> lane hiP
  int linB = linA + 256;                                  // elems 4-7 -> lane hiP+1
  *(uint2*)(lds + swz(linA)) = make_uint2(v.x, v.y);
  *(uint2*)(lds + swz(linB)) = make_uint2(v.z, v.w);
}

template <int KS>
__device__ __forceinline__ bf16x8 ldfrag(const char* lds, int rf, int ks, int lane) {
  int lin = (rf * KS + ks) * 1024 + lane * 16;
  return *(const bf16x8*)(lds + swz(lin));
}

// ---------------------------------------------------------------- prep: casts + weight transposes + d_out zero
__global__ __launch_bounds__(256) void prep(
    const float* __restrict__ s, const float* __restrict__ sp,
    const float* __restrict__ a1h,
    unsigned short* __restrict__ Sb, unsigned short* __restrict__ SPb,
    int* __restrict__ aidx,
    const float* __restrict__ pW0, unsigned short* __restrict__ pW0t,
    const float* __restrict__ pW1, unsigned short* __restrict__ pW1t,
    const float* __restrict__ pW2, unsigned short* __restrict__ pW2t,
    const float* __restrict__ gW0, unsigned short* __restrict__ gW0t,
    const float* __restrict__ gW1, unsigned short* __restrict__ gW1t,
    const float* __restrict__ gW2, unsigned short* __restrict__ gW2t,
    float* __restrict__ out) {
  __shared__ float tile[32][33];
  int b = blockIdx.x;
  if (b < NR) {
    int t = threadIdx.x;
    Sb[(size_t)b * 256 + t] = f2bf(s[(size_t)b * 256 + t]);
    SPb[(size_t)b * 256 + t] = f2bf(sp[(size_t)b * 256 + t]);
    if (t < 4 && a1h[(size_t)b * 4 + t] > 0.5f) aidx[b] = t;
    if (b == 0 && t == 0) out[0] = 0.f;
    return;
  }
  b -= NR;
  const float* W; unsigned short* Wt; int K, N, t;
  if (b < 128)      { W = pW0; Wt = pW0t; K = 256; N = 512; t = b; }
  else if (b < 384) { W = pW1; Wt = pW1t; K = 512; N = 512; t = b - 128; }
  else if (b < 448) { W = pW2; Wt = pW2t; K = 512; N = 128; t = b - 384; }
  else if (b < 576) { W = gW0; Wt = gW0t; K = 256; N = 512; t = b - 448; }
  else if (b < 832) { W = gW1; Wt = gW1t; K = 512; N = 512; t = b - 576; }
  else              { W = gW2; Wt = gW2t; K = 512; N = 128; t = b - 832; }
  int nk = K >> 5;
  int kb = (t % nk) * 32, nb = (t / nk) * 32;
  int tx = threadIdx.x & 31, ty = threadIdx.x >> 5;
#pragma unroll
  for (int r = 0; r < 32; r += 8)
    tile[ty + r][tx] = W[(size_t)(kb + ty + r) * N + nb + tx];
  __syncthreads();
#pragma unroll
  for (int r = 0; r < 32; r += 8)
    Wt[(size_t)(nb + ty + r) * K + kb + tx] = f2bf(tile[tx][ty + r]);
}

// ---------------------------------------------------------------- BM=128 paired GEMM
// z selects (A,W,bias,C). BMODE 1: z==1 adds gW0f action row.
template <bool RELU, int BMODE>
__global__ __launch_bounds__(256) void gemm128(
    const unsigned short* __restrict__ A0, const unsigned short* __restrict__ A1,
    const unsigned short* __restrict__ W0, const unsigned short* __restrict__ W1,
    const float* __restrict__ b0, const float* __restrict__ b1,
    unsigned short* __restrict__ C0, unsigned short* __restrict__ C1,
    int N, int K,
    const int* __restrict__ aidx, const float* __restrict__ gW0f) {
  __shared__ char As[16384];
  __shared__ char Ws[8192];
  const int tid = threadIdx.x, lane = tid & 63, wm = tid >> 6;
  const int bm = blockIdx.x * 128, bn = blockIdx.y * 64;
  const int z = blockIdx.z;
  const unsigned short* A = z ? A1 : A0;
  const unsigned short* W = z ? W1 : W0;
  const float* bias = z ? b1 : b0;
  unsigned short* C = z ? C1 : C0;
  const bool gbias = (BMODE == 1) && (z == 1);

  const int jc = tid >> 3, cc = (tid & 7) * 8;
  uint4 ra[4], rw[2];
#pragma unroll
  for (int u = 0; u < 4; ++u)
    ra[u] = *(const uint4*)&A[(size_t)(bm + u * 32 + jc) * K + cc];
#pragma unroll
  for (int u = 0; u < 2; ++u)
    rw[u] = *(const uint4*)&W[(size_t)(bn + u * 32 + jc) * K + cc];

  f32x4 acc[2][4] = {};
  for (int k0 = 0; k0 < K; k0 += 64) {
    __syncthreads();
#pragma unroll
    for (int u = 0; u < 4; ++u) stage_chunk<2>(As, u * 256 + tid, ra[u]);
#pragma unroll
    for (int u = 0; u < 2; ++u) stage_chunk<2>(Ws, u * 256 + tid, rw[u]);
    if (k0 + 64 < K) {
      int kn = k0 + 64;
#pragma unroll
      for (int u = 0; u < 4; ++u)
        ra[u] = *(const uint4*)&A[(size_t)(bm + u * 32 + jc) * K + kn + cc];
#pragma unroll
      for (int u = 0; u < 2; ++u)
        rw[u] = *(const uint4*)&W[(size_t)(bn + u * 32 + jc) * K + kn + cc];
    }
    __syncthreads();
#pragma unroll
    for (int ks = 0; ks < 2; ++ks) {
      bf16x8 af[2], bfv[4];
#pragma unroll
      for (int f = 0; f < 2; ++f) af[f] = ldfrag<2>(As, wm * 2 + f, ks, lane);
#pragma unroll
      for (int fn = 0; fn < 4; ++fn) bfv[fn] = ldfrag<2>(Ws, fn, ks, lane);
#pragma unroll
      for (int fm = 0; fm < 2; ++fm)
#pragma unroll
        for (int fn = 0; fn < 4; ++fn)
          acc[fm][fn] = __builtin_amdgcn_mfma_f32_16x16x32_bf16(
              af[fm], bfv[fn], acc[fm][fn], 0, 0, 0);
    }
  }

  const int l15 = lane & 15, hi = lane >> 4;
  const int row0 = bm + wm * 32;
#pragma unroll
  for (int fm = 0; fm < 2; ++fm)
#pragma unroll
    for (int fn = 0; fn < 4; ++fn) {
      int col = bn + fn * 16 + l15;
      float bb = bias[col];
      int rbase = row0 + fm * 16 + hi * 4;
#pragma unroll
      for (int e = 0; e < 4; ++e) {
        int row = rbase + e;
        float v = acc[fm][fn][e] + bb;
        if (gbias) v += gW0f[(size_t)(256 + aidx[row]) * N + col];
        if (RELU) v = fmaxf(v, 0.f);
        C[(size_t)row * N + col] = f2bf(v);
      }
    }
}

// ---------------------------------------------------------------- BM=64 paired GEMM (layer 2) + fused row-norm partials
// z=0 -> Zb; z=1 -> Zpb + sqp2[bn/64][row] = sum of squares of this block's 64 cols.
__global__ __launch_bounds__(256) void gemm64_l2(
    const unsigned short* __restrict__ A0, const unsigned short* __restrict__ A1,
    const unsigned short* __restrict__ W0, const unsigned short* __restrict__ W1,
    const float* __restrict__ b0, const float* __restrict__ b1,
    unsigned short* __restrict__ C0, unsigned short* __restrict__ C1,
    float* __restrict__ sqp2, int N, int K) {
  __shared__ char As[8192];
  __shared__ char Ws[8192];
  __shared__ float sqred[2][64];
  const int tid = threadIdx.x, lane = tid & 63, wid = tid >> 6;
  const int wm = wid >> 1, wn = wid & 1;
  const int bm = blockIdx.x * 64, bn = blockIdx.y * 64;
  const int z = blockIdx.z;
  const unsigned short* A = z ? A1 : A0;
  const unsigned short* W = z ? W1 : W0;
  const float* bias = z ? b1 : b0;
  unsigned short* C = z ? C1 : C0;

  const int jc = tid >> 3, cc = (tid & 7) * 8;
  uint4 ra0, ra1, rw0, rw1;
  ra0 = *(const uint4*)&A[(size_t)(bm + jc) * K + cc];
  ra1 = *(const uint4*)&A[(size_t)(bm + 32 + jc) * K + cc];
  rw0 = *(const uint4*)&W[(size_t)(bn + jc) * K + cc];
  rw1 = *(const uint4*)&W[(size_t)(bn + 32 + jc) * K + cc];

  f32x4 acc[2][2] = {};
  for (int k0 = 0; k0 < K; k0 += 64) {
    __syncthreads();
    stage_chunk<2>(As, tid, ra0);
    stage_chunk<2>(As, tid + 256, ra1);
    stage_chunk<2>(Ws, tid, rw0);
    stage_chunk<2>(Ws, tid + 256, rw1);
    if (k0 + 64 < K) {
      int kn = k0 + 64;
      ra0 = *(const uint4*)&A[(size_t)(bm + jc) * K + kn + cc];
      ra1 = *(const uint4*)&A[(size_t)(bm + 32 + jc) * K + kn + cc];
      rw0 = *(const uint4*)&W[(size_t)(bn + jc) * K + kn + cc];
      rw1 = *(const uint4*)&W[(size_t)(bn + 32 + jc) * K + kn + cc];
    }
    __syncthreads();
#pragma unroll
    for (int ks = 0; ks < 2; ++ks) {
      bf16x8 af[2], bfv[2];
#pragma unroll
      for (int f = 0; f < 2; ++f) {
        af[f]  = ldfrag<2>(As, wm * 2 + f, ks, lane);
        bfv[f] = ldfrag<2>(Ws, wn * 2 + f, ks, lane);
      }
#pragma unroll
      for (int fm = 0; fm < 2; ++fm)
#pragma unroll
        for (int fn = 0; fn < 2; ++fn)
          acc[fm][fn] = __builtin_amdgcn_mfma_f32_16x16x32_bf16(
              af[fm], bfv[fn], acc[fm][fn], 0, 0, 0);
    }
  }

  const int l15 = lane & 15, hi = lane >> 4;
  const int row0 = bm + wm * 32, col0 = bn + wn * 32;
  float sq[2][4] = {};
#pragma unroll
  for (int fm = 0; fm < 2; ++fm)
#pragma unroll
    for (int fn = 0; fn < 2; ++fn) {
      int col = col0 + fn * 16 + l15;
      float bb = bias[col];
      int rbase = row0 + fm * 16 + hi * 4;
#pragma unroll
      for (int e = 0; e < 4; ++e) {
        int row = rbase + e;
        float v = acc[fm][fn][e] + bb;
        unsigned short cv = f2bf(v);
        C[(size_t)row * N + col] = cv;
        float vb = bf2f(cv);
        sq[fm][e] += vb * vb;
      }
    }
  if (z == 1) {
#pragma unroll
    for (int fm = 0; fm < 2; ++fm)
#pragma unroll
      for (int e = 0; e < 4; ++e) {
        float v = sq[fm][e];
        v += __shfl_xor(v, 1, 64);
        v += __shfl_xor(v, 2, 64);
        v += __shfl_xor(v, 4, 64);
        v += __shfl_xor(v, 8, 64);
        if (l15 == 0) sqred[wn][wm * 32 + fm * 16 + hi * 4 + e] = v;
      }
    __syncthreads();
    if (tid < 64)
      sqp2[(size_t)blockIdx.y * NR + bm + tid] = sqred[0][tid] + sqred[1][tid];
  }
}

// ---------------------------------------------------------------- logits + deferred softmax
// grid: (NR/64) x NJR. Block: 64 rows x 128 cols; both tiles staged behind one barrier.
__global__ __launch_bounds__(256) void logits_mfma(
    const unsigned short* __restrict__ Zb, const unsigned short* __restrict__ Zpb,
    const float* __restrict__ sqp2, float* __restrict__ wm_,
    float* __restrict__ wsum, float* __restrict__ wdiag) {
  __shared__ char Ps[32768];
  const int tid = threadIdx.x, lane = tid & 63, w = tid >> 6;
  const int l15 = lane & 15, hi4 = (lane >> 4) * 4;
  const int i0 = blockIdx.x * 64, jr = blockIdx.y;
  const int row16 = i0 + w * 16;
  const int jbase = jr * JC;

  // issue both Zp tile loads
  const int jloc = tid >> 4, cloc = (tid & 15) * 8;
  uint4 rv[8];
#pragma unroll
  for (int jt = 0; jt < 2; ++jt) {
    const unsigned short* src = &Zpb[(size_t)(jbase + jt * 64) * ZD];
#pragma unroll
    for (int u = 0; u < 4; ++u)
      rv[jt * 4 + u] = *(const uint4*)&src[(size_t)(jloc + u * 16) * ZD + cloc];
  }
  // A fragments: wave's 16-row Z strip (overlaps with loads above)
  bf16x8 afr[4];
  {
    const unsigned short* zr = &Zb[(size_t)(row16 + l15) * ZD];
#pragma unroll
    for (int ks = 0; ks < 4; ++ks) {
      short4v lo = *(const short4v*)(zr + ks * 32 + hi4);
      short4v hh = *(const short4v*)(zr + ks * 32 + hi4 + 16);
      afr[ks] = __builtin_shufflevector(lo, hh, 0, 1, 2, 3, 4, 5, 6, 7);
    }
  }
  float spv[2][4];
#pragma unroll
  for (int jt = 0; jt < 2; ++jt)
#pragma unroll
    for (int fn = 0; fn < 4; ++fn) {
      int col = jbase + jt * 64 + fn * 16 + l15;
      spv[jt][fn] = sqp2[col] + sqp2[NR + col];
    }
#pragma unroll
  for (int jt = 0; jt < 2; ++jt)
#pragma unroll
    for (int u = 0; u < 4; ++u)
      stage_chunk<4>(Ps + jt * 16384, u * 256 + tid, rv[jt * 4 + u]);
  __syncthreads();

  f32x4 acc[2][4] = {};
#pragma unroll
  for (int jt = 0; jt < 2; ++jt)
#pragma unroll
    for (int ks = 0; ks < 4; ++ks) {
      bf16x8 bfv[4];
#pragma unroll
      for (int fn = 0; fn < 4; ++fn) bfv[fn] = ldfrag<4>(Ps + jt * 16384, fn, ks, lane);
#pragma unroll
      for (int fn = 0; fn < 4; ++fn)
        acc[jt][fn] = __builtin_amdgcn_mfma_f32_16x16x32_bf16(
            afr[ks], bfv[fn], acc[jt][fn], 0, 0, 0);
    }

  // deferred softmax: max-first, single exp pass, cross-lane reduce without exp chains
#pragma unroll
  for (int e = 0; e < 4; ++e) {
    int grow = row16 + hi4 + e;
    float l[8], dd = 0.f;
    float mx = -INFINITY;
#pragma unroll
    for (int jt = 0; jt < 2; ++jt)
#pragma unroll
      for (int fn = 0; fn < 4; ++fn) {
        int col = jbase + jt * 64 + fn * 16 + l15;
        float lv = (2.f * acc[jt][fn][e] - spv[jt][fn]) * INV_T;
        l[jt * 4 + fn] = lv;
        mx = fmaxf(mx, lv);
        if (col == grow) dd = lv;
      }
#pragma unroll
    for (int off = 1; off < 16; off <<= 1) mx = fmaxf(mx, __shfl_xor(mx, off, 64));
    float sum = 0.f;
#pragma unroll
    for (int q = 0; q < 8; ++q) sum += __expf(l[q] - mx);
#pragma unroll
    for (int off = 1; off < 16; off <<= 1) sum += __shfl_xor(sum, off, 64);
    if (l15 == 0) {
      wm_[(size_t)jr * NR + grow] = mx;
      wsum[(size_t)jr * NR + grow] = sum;
    }
    if ((grow >> 7) == jr && l15 == (grow & 15)) wdiag[grow] = dd;
  }
}

// ---------------------------------------------------------------- final combine
__global__ __launch_bounds__(256) void finalize(const float* __restrict__ wm,
    const float* __restrict__ wsum, const float* __restrict__ wdiag,
    float* __restrict__ out) {
  int r = blockIdx.x * 256 + threadIdx.x;
  float mm = wm[r];
  float ss = wsum[r];
#pragma unroll
  for (int p = 1; p < NJR; ++p) {
    float mo = wm[(size_t)p * NR + r];
    float so = wsum[(size_t)p * NR + r];
    float mn = fmaxf(mm, mo);
    ss = ss * __expf(mm - mn) + so * __expf(mo - mn);
    mm = mn;
  }
  float loss_r = mm + logf(ss) - wdiag[r];
  float v = loss_r;
#pragma unroll
  for (int off = 32; off; off >>= 1) v += __shfl_xor(v, off, 64);
  __shared__ float partial[4];
  if ((threadIdx.x & 63) == 0) partial[threadIdx.x >> 6] = v;
  __syncthreads();
  if (threadIdx.x == 0)
    atomicAdd(out, (partial[0] + partial[1] + partial[2] + partial[3]) * (1.0f / (float)NR));
}

// ---------------------------------------------------------------- launch
extern "C" void kernel_launch(void* const* d_in, const int* in_sizes, int n_in,
                              void* d_out, int out_size, void* d_ws, size_t ws_size,
                              hipStream_t stream) {
  const float* s   = (const float*)d_in[0];
  const float* sp  = (const float*)d_in[1];
  const float* a1h = (const float*)d_in[2];
  const float* pW0 = (const float*)d_in[3];
  const float* pb0 = (const float*)d_in[4];
  const float* pW1 = (const float*)d_in[5];
  const float* pb1 = (const float*)d_in[6];
  const float* pW2 = (const float*)d_in[7];
  const float* pb2 = (const float*)d_in[8];
  const float* gW0 = (const float*)d_in[9];
  const float* gb0 = (const float*)d_in[10];
  const float* gW1 = (const float*)d_in[11];
  const float* gb1 = (const float*)d_in[12];
  const float* gW2 = (const float*)d_in[13];
  const float* gb2 = (const float*)d_in[14];

  char* p = (char*)d_ws;
  unsigned short* Sb   = (unsigned short*)p; p += (size_t)NR * 256 * 2;
  unsigned short* SPb  = (unsigned short*)p; p += (size_t)NR * 256 * 2;
  unsigned short* H1   = (unsigned short*)p; p += (size_t)2 * NR * HD * 2;  // [2][NR][HD]
  unsigned short* H2   = (unsigned short*)p; p += (size_t)2 * NR * HD * 2;
  unsigned short* Zall = (unsigned short*)p; p += (size_t)2 * NR * ZD * 2;  // [2][NR][ZD]
  unsigned short* pW0t = (unsigned short*)p; p += (size_t)256 * 512 * 2;
  unsigned short* pW1t = (unsigned short*)p; p += (size_t)512 * 512 * 2;
  unsigned short* pW2t = (unsigned short*)p; p += (size_t)512 * 128 * 2;
  unsigned short* gW0t = (unsigned short*)p; p += (size_t)256 * 512 * 2;
  unsigned short* gW1t = (unsigned short*)p; p += (size_t)512 * 512 * 2;
  unsigned short* gW2t = (unsigned short*)p; p += (size_t)512 * 128 * 2;
  float* sqp2 = (float*)p; p += (size_t)2 * NR * 4;
  float* wm   = (float*)p; p += (size_t)NJR * NR * 4;
  float* wsm  = (float*)p; p += (size_t)NJR * NR * 4;
  float* wdg  = (float*)p; p += (size_t)NR * 4;
  int*   aidx = (int*)p;  p += (size_t)NR * 4;

  unsigned short* H1g = H1 + (size_t)NR * HD;
  unsigned short* H2g = H2 + (size_t)NR * HD;
  unsigned short* Zb  = Zall;
  unsigned short* Zpb = Zall + (size_t)NR * ZD;

  dim3 blk(256);
  prep<<<NR + 896, blk, 0, stream>>>(s, sp, a1h, Sb, SPb, aidx,
                                     pW0, pW0t, pW1, pW1t, pW2, pW2t,
                                     gW0, gW0t, gW1, gW1t, gW2, gW2t,
                                     (float*)d_out);

  gemm128<true, 1><<<dim3(32, 8, 2), blk, 0, stream>>>(
      Sb, SPb, pW0t, gW0t, pb0, gb0, H1, H1g, 512, 256, aidx, gW0);
  gemm128<true, 0><<<dim3(32, 8, 2), blk, 0, stream>>>(
      H1, H1g, pW1t, gW1t, pb1, gb1, H2, H2g, 512, 512, nullptr, nullptr);
  gemm64_l2<<<dim3(64, 2, 2), blk, 0, stream>>>(
      H2, H2g, pW2t, gW2t, pb2, gb2, Zb, Zpb, sqp2, 128, 512);

  logits_mfma<<<dim3(NR / 64, NJR), blk, 0, stream>>>(Zb, Zpb, sqp2, wm, wsm, wdg);
  finalize<<<NR / 256, blk, 0, stream>>>(wm, wsm, wdg, (float*)d_out);
}

// Round 5
// 57.126 us; speedup vs baseline: 6.6182x; 1.1489x over previous
//
#include <hip/hip_runtime.h>
#include <math.h>

#define NR 4096
#define ZD 128
#define HD 512
#define NJR 32
#define INV_T 10.0f

typedef __attribute__((ext_vector_type(8))) short bf16x8;
typedef __attribute__((ext_vector_type(4))) short short4v;
typedef __attribute__((ext_vector_type(4))) float f32x4;

__device__ __forceinline__ unsigned short f2bf(float f) {
  union { float f; unsigned u; } v; v.f = f;
  unsigned r = v.u + 0x7fff + ((v.u >> 16) & 1);
  return (unsigned short)(r >> 16);
}
__device__ __forceinline__ float bf2f(unsigned short b) {
  union { unsigned u; float f; } v; v.u = ((unsigned)b) << 16;
  return v.f;
}

// ======== fragment-major layout ========
// matrix [M][C] (C = k-dim): fragment (rf=r>>4, ks=c>>5) is a 1024B slot at
// (rf*(C>>5)+ks)*1024. Within: lane (hi=c%32/ (4|16), l15=r&15) holds bf16x8 at
// lane*16: elems i<4 -> c=ks*32+hi*4+i ; i>=4 -> c=ks*32+16+hi*4+(i-4).

// ---------------------------------------------------------------- prep
// sections: [0,16) aidx+out0 ; [16,1040) Sb ; [1040,2064) SPb ; [2064,2960) weights
__global__ __launch_bounds__(256) void prep(
    const float* __restrict__ s, const float* __restrict__ sp,
    const float* __restrict__ a1h,
    unsigned short* __restrict__ Sb, unsigned short* __restrict__ SPb,
    int* __restrict__ aidx,
    const float* __restrict__ pW0, unsigned short* __restrict__ pW0t,
    const float* __restrict__ pW1, unsigned short* __restrict__ pW1t,
    const float* __restrict__ pW2, unsigned short* __restrict__ pW2t,
    const float* __restrict__ gW0, unsigned short* __restrict__ gW0t,
    const float* __restrict__ gW1, unsigned short* __restrict__ gW1t,
    const float* __restrict__ gW2, unsigned short* __restrict__ gW2t,
    float* __restrict__ out) {
  int b = blockIdx.x, tid = threadIdx.x;
  if (b < 16) {
    int r = b * 256 + tid;
    int a = 0;
#pragma unroll
    for (int j = 0; j < 4; ++j) if (a1h[(size_t)r * 4 + j] > 0.5f) a = j;
    aidx[r] = a;
    if (b == 0 && tid == 0) out[0] = 0.f;
    return;
  }
  const int idx8 = tid & 127;
  const int h = idx8 & 1, p = idx8 >> 1, hi = p >> 4, l15 = p & 15;
  if (b < 2064) {
    // activations: K=256, KS=8
    const float* src = (b < 1040) ? s : sp;
    unsigned short* dst = (b < 1040) ? Sb : SPb;
    int lb = (b < 1040) ? b - 16 : b - 1040;
    int s0 = lb * 2 + (tid >> 7);
    int rf = s0 >> 3, ks = s0 & 7;
    int row = rf * 16 + l15, c0 = ks * 32 + hi * 4 + h * 16;
    float4 v = *(const float4*)&src[(size_t)row * 256 + c0];
    short4v o = { (short)f2bf(v.x), (short)f2bf(v.y), (short)f2bf(v.z), (short)f2bf(v.w) };
    *(short4v*)((char*)dst + (size_t)s0 * 1024 + idx8 * 8) = o;
    return;
  }
  int local = b - 2064;
  const float* W; unsigned short* Wt; int N, ksh;
  if (local < 128)      { W = pW0; Wt = pW0t; N = 512; ksh = 3; }
  else if (local < 384) { W = pW1; Wt = pW1t; N = 512; ksh = 4; local -= 128; }
  else if (local < 448) { W = pW2; Wt = pW2t; N = 128; ksh = 4; local -= 384; }
  else if (local < 576) { W = gW0; Wt = gW0t; N = 512; ksh = 3; local -= 448; }
  else if (local < 832) { W = gW1; Wt = gW1t; N = 512; ksh = 4; local -= 576; }
  else                  { W = gW2; Wt = gW2t; N = 128; ksh = 4; local -= 832; }
  int s0 = local * 2 + (tid >> 7);
  int rf = s0 >> ksh, ks = s0 & ((1 << ksh) - 1);
  int n = rf * 16 + l15, k0 = ks * 32 + hi * 4 + h * 16;
  short4v o = { (short)f2bf(W[(size_t)(k0 + 0) * N + n]),
                (short)f2bf(W[(size_t)(k0 + 1) * N + n]),
                (short)f2bf(W[(size_t)(k0 + 2) * N + n]),
                (short)f2bf(W[(size_t)(k0 + 3) * N + n]) };
  *(short4v*)((char*)Wt + (size_t)s0 * 1024 + idx8 * 8) = o;
}

// ---------------------------------------------------------------- fragment-major GEMM (no LDS)
// block: 4 waves x (32 rows); wave tile 32 x (FN*16) cols. All tensors frag-major.
// acc = mfma(wfrag, afrag): lane&15 = out-row, hi*4+e = out-col  -> direct frag store.
template <bool RELU, bool GB, int FN, bool SQ>
__global__ __launch_bounds__(256) void gemm_fm(
    const unsigned short* __restrict__ A0, const unsigned short* __restrict__ A1,
    const unsigned short* __restrict__ W0, const unsigned short* __restrict__ W1,
    const float* __restrict__ b0, const float* __restrict__ b1,
    unsigned short* __restrict__ C0, unsigned short* __restrict__ C1,
    float* __restrict__ sqp2, int N, int K,
    const int* __restrict__ aidx, const float* __restrict__ gW0f) {
  const int tid = threadIdx.x, lane = tid & 63, w = tid >> 6;
  const int z = blockIdx.z;
  const char* Ab = (const char*)(z ? A1 : A0);
  const char* Wb = (const char*)(z ? W1 : W0);
  const float* bias = z ? b1 : b0;
  char* Cb = (char*)(z ? C1 : C0);
  const int KS = K >> 5;
  const int bm = blockIdx.x * 128 + w * 32;
  const int bn = blockIdx.y * (FN * 16);
  const int rowf = bm >> 4, colf = bn >> 4;
  const int lane16 = lane * 16;

  f32x4 acc[2][FN] = {};
#pragma unroll 4
  for (int ks = 0; ks < KS; ++ks) {
    bf16x8 af0 = *(const bf16x8*)(Ab + ((((size_t)rowf) * KS + ks) << 10) + lane16);
    bf16x8 af1 = *(const bf16x8*)(Ab + ((((size_t)rowf + 1) * KS + ks) << 10) + lane16);
    bf16x8 wf[FN];
#pragma unroll
    for (int fn = 0; fn < FN; ++fn)
      wf[fn] = *(const bf16x8*)(Wb + ((((size_t)colf + fn) * KS + ks) << 10) + lane16);
#pragma unroll
    for (int fn = 0; fn < FN; ++fn) {
      acc[0][fn] = __builtin_amdgcn_mfma_f32_16x16x32_bf16(wf[fn], af0, acc[0][fn], 0, 0, 0);
      acc[1][fn] = __builtin_amdgcn_mfma_f32_16x16x32_bf16(wf[fn], af1, acc[1][fn], 0, 0, 0);
    }
  }

  const int l15 = lane & 15, hi = lane >> 4;
  const int NS = N >> 5;
  float sq[2] = {0.f, 0.f};
  int ar[2];
  if (GB) {
    ar[0] = aidx[bm + l15];
    ar[1] = aidx[bm + 16 + l15];
  }
#pragma unroll
  for (int fm = 0; fm < 2; ++fm)
#pragma unroll
    for (int q = 0; q < FN / 2; ++q) {
      float4 bi0 = *(const float4*)&bias[bn + q * 32 + hi * 4];
      float4 bi1 = *(const float4*)&bias[bn + q * 32 + 16 + hi * 4];
      float v[8] = { acc[fm][2 * q][0] + bi0.x, acc[fm][2 * q][1] + bi0.y,
                     acc[fm][2 * q][2] + bi0.z, acc[fm][2 * q][3] + bi0.w,
                     acc[fm][2 * q + 1][0] + bi1.x, acc[fm][2 * q + 1][1] + bi1.y,
                     acc[fm][2 * q + 1][2] + bi1.z, acc[fm][2 * q + 1][3] + bi1.w };
      if (GB && z == 1) {
        float4 g0 = *(const float4*)&gW0f[(size_t)(256 + ar[fm]) * N + bn + q * 32 + hi * 4];
        float4 g1 = *(const float4*)&gW0f[(size_t)(256 + ar[fm]) * N + bn + q * 32 + 16 + hi * 4];
        v[0] += g0.x; v[1] += g0.y; v[2] += g0.z; v[3] += g0.w;
        v[4] += g1.x; v[5] += g1.y; v[6] += g1.z; v[7] += g1.w;
      }
      bf16x8 r;
#pragma unroll
      for (int i = 0; i < 8; ++i) {
        float vv = RELU ? fmaxf(v[i], 0.f) : v[i];
        unsigned short cv = f2bf(vv);
        r[i] = (short)cv;
        if (SQ) { float vb = bf2f(cv); sq[fm] += vb * vb; }
      }
      *(bf16x8*)(Cb + ((((size_t)rowf + fm) * NS + (bn >> 5) + q) << 10) + lane16) = r;
    }
  if (SQ && z == 1) {
#pragma unroll
    for (int fm = 0; fm < 2; ++fm) {
      float t = sq[fm];
      t += __shfl_xor(t, 16, 64);
      t += __shfl_xor(t, 32, 64);
      if (lane < 16) sqp2[(size_t)(bn >> 5) * NR + bm + fm * 16 + lane] = t;
    }
  }
}

// ---------------------------------------------------------------- logits + deferred softmax (no LDS)
// grid (NR/64, NJR). wave: 16 Z-rows x 128 Zp-cols. All frag-major, direct loads.
__global__ __launch_bounds__(256) void logits_fm(
    const unsigned short* __restrict__ Zb, const unsigned short* __restrict__ Zpb,
    const float* __restrict__ sqp2, float* __restrict__ wm_,
    float* __restrict__ wsum, float* __restrict__ wdiag) {
  const int tid = threadIdx.x, lane = tid & 63, w = tid >> 6;
  const int l15 = lane & 15, hi4 = (lane >> 4) * 4;
  const int i0 = blockIdx.x * 64, jr = blockIdx.y;
  const int row16 = i0 + w * 16;
  const int jbase = jr * 128;
  const int lane16 = lane * 16;
  const char* Zc = (const char*)Zb;
  const char* Pc = (const char*)Zpb;
  const int rfA = row16 >> 4;

  bf16x8 afr[4];
#pragma unroll
  for (int ks = 0; ks < 4; ++ks)
    afr[ks] = *(const bf16x8*)(Zc + ((((size_t)rfA) * 4 + ks) << 10) + lane16);

  f32x4 acc[2][4] = {};
#pragma unroll
  for (int jt = 0; jt < 2; ++jt)
#pragma unroll
    for (int fn = 0; fn < 4; ++fn) {
      const int jf = (jbase >> 4) + jt * 4 + fn;
#pragma unroll
      for (int ks = 0; ks < 4; ++ks) {
        bf16x8 bfv = *(const bf16x8*)(Pc + ((((size_t)jf) * 4 + ks) << 10) + lane16);
        acc[jt][fn] = __builtin_amdgcn_mfma_f32_16x16x32_bf16(afr[ks], bfv, acc[jt][fn], 0, 0, 0);
      }
    }

  float spv[2][4];
#pragma unroll
  for (int jt = 0; jt < 2; ++jt)
#pragma unroll
    for (int fn = 0; fn < 4; ++fn) {
      int col = jbase + jt * 64 + fn * 16 + l15;
      spv[jt][fn] = sqp2[col] + sqp2[NR + col] + sqp2[2 * NR + col] + sqp2[3 * NR + col];
    }

#pragma unroll
  for (int e = 0; e < 4; ++e) {
    int grow = row16 + hi4 + e;
    float l[8], dd = 0.f;
    float mx = -INFINITY;
#pragma unroll
    for (int jt = 0; jt < 2; ++jt)
#pragma unroll
      for (int fn = 0; fn < 4; ++fn) {
        int col = jbase + jt * 64 + fn * 16 + l15;
        float lv = (2.f * acc[jt][fn][e] - spv[jt][fn]) * INV_T;
        l[jt * 4 + fn] = lv;
        mx = fmaxf(mx, lv);
        if (col == grow) dd = lv;
      }
#pragma unroll
    for (int off = 1; off < 16; off <<= 1) mx = fmaxf(mx, __shfl_xor(mx, off, 64));
    float sum = 0.f;
#pragma unroll
    for (int q = 0; q < 8; ++q) sum += __expf(l[q] - mx);
#pragma unroll
    for (int off = 1; off < 16; off <<= 1) sum += __shfl_xor(sum, off, 64);
    if (l15 == 0) {
      wm_[(size_t)jr * NR + grow] = mx;
      wsum[(size_t)jr * NR + grow] = sum;
    }
    if ((grow >> 7) == jr && l15 == (grow & 15)) wdiag[grow] = dd;
  }
}

// ---------------------------------------------------------------- final combine
__global__ __launch_bounds__(256) void finalize(const float* __restrict__ wm,
    const float* __restrict__ wsum, const float* __restrict__ wdiag,
    float* __restrict__ out) {
  int r = blockIdx.x * 256 + threadIdx.x;
  float mm = wm[r];
  float ss = wsum[r];
#pragma unroll
  for (int p = 1; p < NJR; ++p) {
    float mo = wm[(size_t)p * NR + r];
    float so = wsum[(size_t)p * NR + r];
    float mn = fmaxf(mm, mo);
    ss = ss * __expf(mm - mn) + so * __expf(mo - mn);
    mm = mn;
  }
  float loss_r = mm + logf(ss) - wdiag[r];
  float v = loss_r;
#pragma unroll
  for (int off = 32; off; off >>= 1) v += __shfl_xor(v, off, 64);
  __shared__ float partial[4];
  if ((threadIdx.x & 63) == 0) partial[threadIdx.x >> 6] = v;
  __syncthreads();
  if (threadIdx.x == 0)
    atomicAdd(out, (partial[0] + partial[1] + partial[2] + partial[3]) * (1.0f / (float)NR));
}

// ---------------------------------------------------------------- launch
extern "C" void kernel_launch(void* const* d_in, const int* in_sizes, int n_in,
                              void* d_out, int out_size, void* d_ws, size_t ws_size,
                              hipStream_t stream) {
  const float* s   = (const float*)d_in[0];
  const float* sp  = (const float*)d_in[1];
  const float* a1h = (const float*)d_in[2];
  const float* pW0 = (const float*)d_in[3];
  const float* pb0 = (const float*)d_in[4];
  const float* pW1 = (const float*)d_in[5];
  const float* pb1 = (const float*)d_in[6];
  const float* pW2 = (const float*)d_in[7];
  const float* pb2 = (const float*)d_in[8];
  const float* gW0 = (const float*)d_in[9];
  const float* gb0 = (const float*)d_in[10];
  const float* gW1 = (const float*)d_in[11];
  const float* gb1 = (const float*)d_in[12];
  const float* gW2 = (const float*)d_in[13];
  const float* gb2 = (const float*)d_in[14];

  char* p = (char*)d_ws;
  unsigned short* Sb   = (unsigned short*)p; p += (size_t)NR * 256 * 2;
  unsigned short* SPb  = (unsigned short*)p; p += (size_t)NR * 256 * 2;
  unsigned short* H1   = (unsigned short*)p; p += (size_t)2 * NR * HD * 2;
  unsigned short* H2   = (unsigned short*)p; p += (size_t)2 * NR * HD * 2;
  unsigned short* Zall = (unsigned short*)p; p += (size_t)2 * NR * ZD * 2;
  unsigned short* pW0t = (unsigned short*)p; p += (size_t)256 * 512 * 2;
  unsigned short* pW1t = (unsigned short*)p; p += (size_t)512 * 512 * 2;
  unsigned short* pW2t = (unsigned short*)p; p += (size_t)512 * 128 * 2;
  unsigned short* gW0t = (unsigned short*)p; p += (size_t)256 * 512 * 2;
  unsigned short* gW1t = (unsigned short*)p; p += (size_t)512 * 512 * 2;
  unsigned short* gW2t = (unsigned short*)p; p += (size_t)512 * 128 * 2;
  float* sqp2 = (float*)p; p += (size_t)4 * NR * 4;
  float* wm   = (float*)p; p += (size_t)NJR * NR * 4;
  float* wsm  = (float*)p; p += (size_t)NJR * NR * 4;
  float* wdg  = (float*)p; p += (size_t)NR * 4;
  int*   aidx = (int*)p;  p += (size_t)NR * 4;

  unsigned short* H1g = H1 + (size_t)NR * HD;
  unsigned short* H2g = H2 + (size_t)NR * HD;
  unsigned short* Zb  = Zall;
  unsigned short* Zpb = Zall + (size_t)NR * ZD;

  dim3 blk(256);
  prep<<<2960, blk, 0, stream>>>(s, sp, a1h, Sb, SPb, aidx,
                                 pW0, pW0t, pW1, pW1t, pW2, pW2t,
                                 gW0, gW0t, gW1, gW1t, gW2, gW2t,
                                 (float*)d_out);

  gemm_fm<true, true, 4, false><<<dim3(32, 8, 2), blk, 0, stream>>>(
      Sb, SPb, pW0t, gW0t, pb0, gb0, H1, H1g, nullptr, 512, 256, aidx, gW0);
  gemm_fm<true, false, 4, false><<<dim3(32, 8, 2), blk, 0, stream>>>(
      H1, H1g, pW1t, gW1t, pb1, gb1, H2, H2g, nullptr, 512, 512, nullptr, nullptr);
  gemm_fm<false, false, 2, true><<<dim3(32, 4, 2), blk, 0, stream>>>(
      H2, H2g, pW2t, gW2t, pb2, gb2, Zb, Zpb, sqp2, 128, 512, nullptr, nullptr);

  logits_fm<<<dim3(NR / 64, NJR), blk, 0, stream>>>(Zb, Zpb, sqp2, wm, wsm, wdg);
  finalize<<<NR / 256, blk, 0, stream>>>(wm, wsm, wdg, (float*)d_out);
}

// Round 6
// 56.402 us; speedup vs baseline: 6.7032x; 1.0128x over previous
//
#include <hip/hip_runtime.h>
#include <math.h>

#define NR 4096
#define ZD 128
#define HD 512
#define NJR 32
#define INV_T 10.0f

typedef __attribute__((ext_vector_type(8))) short bf16x8;
typedef __attribute__((ext_vector_type(4))) short short4v;
typedef __attribute__((ext_vector_type(4))) float f32x4;

typedef const unsigned int __attribute__((address_space(1)))* gas_t;
typedef unsigned int __attribute__((address_space(3)))* las_t;

__device__ __forceinline__ unsigned short f2bf(float f) {
  union { float f; unsigned u; } v; v.f = f;
  unsigned r = v.u + 0x7fff + ((v.u >> 16) & 1);
  return (unsigned short)(r >> 16);
}
__device__ __forceinline__ float bf2f(unsigned short b) {
  union { unsigned u; float f; } v; v.u = ((unsigned)b) << 16;
  return v.f;
}

// ======== fragment-major layout ========
// matrix [M][K]: fragment (rf=r>>4, ks=c>>5) = 1024B slot at (rf*(K>>5)+ks)*1024.
// lane l holds bf16x8 at lane*16: row = rf*16+(l&15), cols ks*32 + (l>>4)*4 + {0..3, 16..19}.

// ---------------------------------------------------------------- prep (unchanged from R5)
__global__ __launch_bounds__(256) void prep(
    const float* __restrict__ s, const float* __restrict__ sp,
    const float* __restrict__ a1h,
    unsigned short* __restrict__ Sb, unsigned short* __restrict__ SPb,
    int* __restrict__ aidx,
    const float* __restrict__ pW0, unsigned short* __restrict__ pW0t,
    const float* __restrict__ pW1, unsigned short* __restrict__ pW1t,
    const float* __restrict__ pW2, unsigned short* __restrict__ pW2t,
    const float* __restrict__ gW0, unsigned short* __restrict__ gW0t,
    const float* __restrict__ gW1, unsigned short* __restrict__ gW1t,
    const float* __restrict__ gW2, unsigned short* __restrict__ gW2t,
    float* __restrict__ out) {
  int b = blockIdx.x, tid = threadIdx.x;
  if (b < 16) {
    int r = b * 256 + tid;
    int a = 0;
#pragma unroll
    for (int j = 0; j < 4; ++j) if (a1h[(size_t)r * 4 + j] > 0.5f) a = j;
    aidx[r] = a;
    if (b == 0 && tid == 0) out[0] = 0.f;
    return;
  }
  const int idx8 = tid & 127;
  const int h = idx8 & 1, p = idx8 >> 1, hi = p >> 4, l15 = p & 15;
  if (b < 2064) {
    const float* src = (b < 1040) ? s : sp;
    unsigned short* dst = (b < 1040) ? Sb : SPb;
    int lb = (b < 1040) ? b - 16 : b - 1040;
    int s0 = lb * 2 + (tid >> 7);
    int rf = s0 >> 3, ks = s0 & 7;
    int row = rf * 16 + l15, c0 = ks * 32 + hi * 4 + h * 16;
    float4 v = *(const float4*)&src[(size_t)row * 256 + c0];
    short4v o = { (short)f2bf(v.x), (short)f2bf(v.y), (short)f2bf(v.z), (short)f2bf(v.w) };
    *(short4v*)((char*)dst + (size_t)s0 * 1024 + idx8 * 8) = o;
    return;
  }
  int local = b - 2064;
  const float* W; unsigned short* Wt; int N, ksh;
  if (local < 128)      { W = pW0; Wt = pW0t; N = 512; ksh = 3; }
  else if (local < 384) { W = pW1; Wt = pW1t; N = 512; ksh = 4; local -= 128; }
  else if (local < 448) { W = pW2; Wt = pW2t; N = 128; ksh = 4; local -= 384; }
  else if (local < 576) { W = gW0; Wt = gW0t; N = 512; ksh = 3; local -= 448; }
  else if (local < 832) { W = gW1; Wt = gW1t; N = 512; ksh = 4; local -= 576; }
  else                  { W = gW2; Wt = gW2t; N = 128; ksh = 4; local -= 832; }
  int s0 = local * 2 + (tid >> 7);
  int rf = s0 >> ksh, ks = s0 & ((1 << ksh) - 1);
  int n = rf * 16 + l15, k0 = ks * 32 + hi * 4 + h * 16;
  short4v o = { (short)f2bf(W[(size_t)(k0 + 0) * N + n]),
                (short)f2bf(W[(size_t)(k0 + 1) * N + n]),
                (short)f2bf(W[(size_t)(k0 + 2) * N + n]),
                (short)f2bf(W[(size_t)(k0 + 3) * N + n]) };
  *(short4v*)((char*)Wt + (size_t)s0 * 1024 + idx8 * 8) = o;
}

// ---------------------------------------------------------------- LDS double-buffered GEMM
// 128x128 block tile, BK=64, 4 waves (2x2), 64x64 per wave (4x4 fragments).
// global_load_lds staging (frag-major => linear), counted vmcnt, raw barriers.
template <bool RELU, bool GB, bool SQ, int K>
__global__ __launch_bounds__(256) void gemm_lds(
    const unsigned short* __restrict__ A0, const unsigned short* __restrict__ A1,
    const unsigned short* __restrict__ W0, const unsigned short* __restrict__ W1,
    const float* __restrict__ b0, const float* __restrict__ b1,
    unsigned short* __restrict__ C0, unsigned short* __restrict__ C1,
    float* __restrict__ sqp2, int N,
    const int* __restrict__ aidx, const float* __restrict__ gW0f) {
  __shared__ char As[2][16384];
  __shared__ char Bs[2][16384];
  constexpr int KS = K >> 5;
  constexpr int NSTEP = K >> 6;
  const int tid = threadIdx.x, lane = tid & 63, w = tid >> 6;
  const int wm = w >> 1, wn = w & 1;
  const int z = blockIdx.z;
  const char* Ab = (const char*)(z ? A1 : A0);
  const char* Wb = (const char*)(z ? W1 : W0);
  const float* bias = z ? b1 : b0;
  char* Cb = (char*)(z ? C1 : C0);
  const int bm = blockIdx.x * 128, bn = blockIdx.y * 128;
  const int lane16 = lane * 16;

  // staging sources: wave stages local slots w*4+u (slot = rf*2 + kss)
  const char* asrc[4];
  const char* bsrc[4];
#pragma unroll
  for (int u = 0; u < 4; ++u) {
    const int sl = w * 4 + u;
    asrc[u] = Ab + (size_t)(((bm >> 4) + (sl >> 1)) * KS + (sl & 1)) * 1024 + lane16;
    bsrc[u] = Wb + (size_t)(((bn >> 4) + (sl >> 1)) * KS + (sl & 1)) * 1024 + lane16;
  }
  auto stage = [&](int buf, int st) {
    const int so = st * 2048;            // +2 ks-slots per K-step
#pragma unroll
    for (int u = 0; u < 4; ++u) {
      const int sl = w * 4 + u;
      __builtin_amdgcn_global_load_lds((gas_t)(asrc[u] + so), (las_t)&As[buf][sl * 1024], 16, 0, 0);
      __builtin_amdgcn_global_load_lds((gas_t)(bsrc[u] + so), (las_t)&Bs[buf][sl * 1024], 16, 0, 0);
    }
  };

  f32x4 acc[4][4] = {};
  stage(0, 0);
#pragma unroll
  for (int st = 0; st < NSTEP; ++st) {
    const int buf = st & 1;
    if (st + 1 < NSTEP) {
      stage(buf ^ 1, st + 1);                       // next tile in flight during compute
      asm volatile("s_waitcnt vmcnt(8)" ::: "memory");   // only current tile's 8 drained
    } else {
      asm volatile("s_waitcnt vmcnt(0)" ::: "memory");
    }
    __builtin_amdgcn_s_barrier();
    __builtin_amdgcn_sched_barrier(0);
#pragma unroll
    for (int kss = 0; kss < 2; ++kss) {
      bf16x8 af[4], bfv[4];
#pragma unroll
      for (int i = 0; i < 4; ++i)
        af[i] = *(const bf16x8*)(&As[buf][((wm * 4 + i) * 2 + kss) * 1024 + lane16]);
#pragma unroll
      for (int j = 0; j < 4; ++j)
        bfv[j] = *(const bf16x8*)(&Bs[buf][((wn * 4 + j) * 2 + kss) * 1024 + lane16]);
#pragma unroll
      for (int i = 0; i < 4; ++i)
#pragma unroll
        for (int j = 0; j < 4; ++j)
          acc[i][j] = __builtin_amdgcn_mfma_f32_16x16x32_bf16(bfv[j], af[i], acc[i][j], 0, 0, 0);
    }
    __builtin_amdgcn_sched_barrier(0);
    __builtin_amdgcn_s_barrier();
  }

  // epilogue: lane&15 = out-row, regs = out-cols -> direct frag-major store
  const int l15 = lane & 15, hi = lane >> 4;
  const int NS = N >> 5;
  const int row0 = bm + wm * 64;
  const int col0 = bn + wn * 64;
  float sq[4] = {0.f, 0.f, 0.f, 0.f};
  int ar[4] = {0, 0, 0, 0};
  if (GB && z == 1) {
#pragma unroll
    for (int i = 0; i < 4; ++i) ar[i] = aidx[row0 + i * 16 + l15];
  }
#pragma unroll
  for (int i = 0; i < 4; ++i) {
    const int rfC = (row0 >> 4) + i;
#pragma unroll
    for (int q = 0; q < 2; ++q) {
      float4 bi0 = *(const float4*)&bias[col0 + q * 32 + hi * 4];
      float4 bi1 = *(const float4*)&bias[col0 + q * 32 + 16 + hi * 4];
      float v[8] = { acc[i][2 * q][0] + bi0.x, acc[i][2 * q][1] + bi0.y,
                     acc[i][2 * q][2] + bi0.z, acc[i][2 * q][3] + bi0.w,
                     acc[i][2 * q + 1][0] + bi1.x, acc[i][2 * q + 1][1] + bi1.y,
                     acc[i][2 * q + 1][2] + bi1.z, acc[i][2 * q + 1][3] + bi1.w };
      if (GB && z == 1) {
        float4 g0 = *(const float4*)&gW0f[(size_t)(256 + ar[i]) * N + col0 + q * 32 + hi * 4];
        float4 g1 = *(const float4*)&gW0f[(size_t)(256 + ar[i]) * N + col0 + q * 32 + 16 + hi * 4];
        v[0] += g0.x; v[1] += g0.y; v[2] += g0.z; v[3] += g0.w;
        v[4] += g1.x; v[5] += g1.y; v[6] += g1.z; v[7] += g1.w;
      }
      bf16x8 r;
#pragma unroll
      for (int t = 0; t < 8; ++t) {
        float vv = RELU ? fmaxf(v[t], 0.f) : v[t];
        unsigned short cv = f2bf(vv);
        r[t] = (short)cv;
        if (SQ) { float vb = bf2f(cv); sq[i] += vb * vb; }
      }
      *(bf16x8*)(Cb + (size_t)(rfC * NS + ((col0 + q * 32) >> 5)) * 1024 + lane16) = r;
    }
  }
  if (SQ && z == 1) {
#pragma unroll
    for (int i = 0; i < 4; ++i) {
      float t = sq[i];
      t += __shfl_xor(t, 16, 64);
      t += __shfl_xor(t, 32, 64);
      if (lane < 16) sqp2[(size_t)wn * NR + row0 + i * 16 + lane] = t;
    }
  }
}

// ---------------------------------------------------------------- logits (swapped MFMA, LDS-staged Zp)
// grid (NR/128, NJR). Wave: 32 Z-rows x 128 Zp-cols. Swapped operands:
// lane&15 = Z-row, regs = 32 j-values -> row softmax is in-register + 2 shuffles.
__global__ __launch_bounds__(256) void logits_fm(
    const unsigned short* __restrict__ Zb, const unsigned short* __restrict__ Zpb,
    const float* __restrict__ sqp2, float* __restrict__ wm_,
    float* __restrict__ wsum, float* __restrict__ wdiag) {
  __shared__ char Ps[32768];
  const int tid = threadIdx.x, lane = tid & 63, w = tid >> 6;
  const int l15 = lane & 15, hi = lane >> 4;
  const int i0 = blockIdx.x * 128, jr = blockIdx.y;
  const int row32 = i0 + w * 32;
  const int jbase = jr * 128;
  const int lane16 = lane * 16;
  const char* Zc = (const char*)Zb;
  const char* Pc = (const char*)Zpb;

  // stage the 32KB Zp row-block (contiguous in frag-major global)
  {
    const char* src = Pc + (size_t)jbase * 256;
#pragma unroll
    for (int u = 0; u < 8; ++u) {
      const int sl = w * 8 + u;
      __builtin_amdgcn_global_load_lds((gas_t)(src + sl * 1024 + lane16),
                                       (las_t)&Ps[sl * 1024], 16, 0, 0);
    }
  }
  // Z strip fragments (2 rf x 4 ks) direct from global
  bf16x8 afr[2][4];
#pragma unroll
  for (int rf = 0; rf < 2; ++rf)
#pragma unroll
    for (int ks = 0; ks < 4; ++ks)
      afr[rf][ks] = *(const bf16x8*)(Zc + (size_t)(((row32 >> 4) + rf) * 4 + ks) * 1024 + lane16);

  asm volatile("s_waitcnt vmcnt(0)" ::: "memory");
  __builtin_amdgcn_s_barrier();
  __builtin_amdgcn_sched_barrier(0);

  f32x4 acc[2][8] = {};
#pragma unroll
  for (int ks = 0; ks < 4; ++ks)
#pragma unroll
    for (int jf = 0; jf < 8; ++jf) {
      bf16x8 bfv = *(const bf16x8*)(&Ps[(jf * 4 + ks) * 1024 + lane16]);
      acc[0][jf] = __builtin_amdgcn_mfma_f32_16x16x32_bf16(bfv, afr[0][ks], acc[0][jf], 0, 0, 0);
      acc[1][jf] = __builtin_amdgcn_mfma_f32_16x16x32_bf16(bfv, afr[1][ks], acc[1][jf], 0, 0, 0);
    }

  // ||zp_j||^2 for lane's j's: j = jbase + jf*16 + hi*4 + e
  f32x4 spq[8];
#pragma unroll
  for (int jf = 0; jf < 8; ++jf) {
    float4 s0 = *(const float4*)&sqp2[jbase + jf * 16 + hi * 4];
    float4 s1 = *(const float4*)&sqp2[NR + jbase + jf * 16 + hi * 4];
    spq[jf][0] = s0.x + s1.x; spq[jf][1] = s0.y + s1.y;
    spq[jf][2] = s0.z + s1.z; spq[jf][3] = s0.w + s1.w;
  }

#pragma unroll
  for (int rf = 0; rf < 2; ++rf) {
    const int grow = row32 + rf * 16 + l15;
    float mx = -INFINITY, dd = 0.f;
    bool hasd = false;
#pragma unroll
    for (int jf = 0; jf < 8; ++jf)
#pragma unroll
      for (int e = 0; e < 4; ++e) {
        const int j = jbase + jf * 16 + hi * 4 + e;
        float lv = (2.f * acc[rf][jf][e] - spq[jf][e]) * INV_T;
        acc[rf][jf][e] = lv;
        mx = fmaxf(mx, lv);
        if (j == grow) { dd = lv; hasd = true; }
      }
    mx = fmaxf(mx, __shfl_xor(mx, 16, 64));
    mx = fmaxf(mx, __shfl_xor(mx, 32, 64));
    float sum = 0.f;
#pragma unroll
    for (int jf = 0; jf < 8; ++jf)
#pragma unroll
      for (int e = 0; e < 4; ++e) sum += __expf(acc[rf][jf][e] - mx);
    sum += __shfl_xor(sum, 16, 64);
    sum += __shfl_xor(sum, 32, 64);
    if (hi == 0) {
      wm_[(size_t)jr * NR + grow] = mx;
      wsum[(size_t)jr * NR + grow] = sum;
    }
    if (hasd) wdiag[grow] = dd;
  }
}

// ---------------------------------------------------------------- final combine
__global__ __launch_bounds__(256) void finalize(const float* __restrict__ wm,
    const float* __restrict__ wsum, const float* __restrict__ wdiag,
    float* __restrict__ out) {
  int r = blockIdx.x * 256 + threadIdx.x;
  float mm = wm[r];
  float ss = wsum[r];
#pragma unroll
  for (int p = 1; p < NJR; ++p) {
    float mo = wm[(size_t)p * NR + r];
    float so = wsum[(size_t)p * NR + r];
    float mn = fmaxf(mm, mo);
    ss = ss * __expf(mm - mn) + so * __expf(mo - mn);
    mm = mn;
  }
  float loss_r = mm + logf(ss) - wdiag[r];
  float v = loss_r;
#pragma unroll
  for (int off = 32; off; off >>= 1) v += __shfl_xor(v, off, 64);
  __shared__ float partial[4];
  if ((threadIdx.x & 63) == 0) partial[threadIdx.x >> 6] = v;
  __syncthreads();
  if (threadIdx.x == 0)
    atomicAdd(out, (partial[0] + partial[1] + partial[2] + partial[3]) * (1.0f / (float)NR));
}

// ---------------------------------------------------------------- launch
extern "C" void kernel_launch(void* const* d_in, const int* in_sizes, int n_in,
                              void* d_out, int out_size, void* d_ws, size_t ws_size,
                              hipStream_t stream) {
  const float* s   = (const float*)d_in[0];
  const float* sp  = (const float*)d_in[1];
  const float* a1h = (const float*)d_in[2];
  const float* pW0 = (const float*)d_in[3];
  const float* pb0 = (const float*)d_in[4];
  const float* pW1 = (const float*)d_in[5];
  const float* pb1 = (const float*)d_in[6];
  const float* pW2 = (const float*)d_in[7];
  const float* pb2 = (const float*)d_in[8];
  const float* gW0 = (const float*)d_in[9];
  const float* gb0 = (const float*)d_in[10];
  const float* gW1 = (const float*)d_in[11];
  const float* gb1 = (const float*)d_in[12];
  const float* gW2 = (const float*)d_in[13];
  const float* gb2 = (const float*)d_in[14];

  char* p = (char*)d_ws;
  unsigned short* Sb   = (unsigned short*)p; p += (size_t)NR * 256 * 2;
  unsigned short* SPb  = (unsigned short*)p; p += (size_t)NR * 256 * 2;
  unsigned short* H1   = (unsigned short*)p; p += (size_t)2 * NR * HD * 2;
  unsigned short* H2   = (unsigned short*)p; p += (size_t)2 * NR * HD * 2;
  unsigned short* Zall = (unsigned short*)p; p += (size_t)2 * NR * ZD * 2;
  unsigned short* pW0t = (unsigned short*)p; p += (size_t)256 * 512 * 2;
  unsigned short* pW1t = (unsigned short*)p; p += (size_t)512 * 512 * 2;
  unsigned short* pW2t = (unsigned short*)p; p += (size_t)512 * 128 * 2;
  unsigned short* gW0t = (unsigned short*)p; p += (size_t)256 * 512 * 2;
  unsigned short* gW1t = (unsigned short*)p; p += (size_t)512 * 512 * 2;
  unsigned short* gW2t = (unsigned short*)p; p += (size_t)512 * 128 * 2;
  float* sqp2 = (float*)p; p += (size_t)4 * NR * 4;
  float* wm   = (float*)p; p += (size_t)NJR * NR * 4;
  float* wsm  = (float*)p; p += (size_t)NJR * NR * 4;
  float* wdg  = (float*)p; p += (size_t)NR * 4;
  int*   aidx = (int*)p;  p += (size_t)NR * 4;

  unsigned short* H1g = H1 + (size_t)NR * HD;
  unsigned short* H2g = H2 + (size_t)NR * HD;
  unsigned short* Zb  = Zall;
  unsigned short* Zpb = Zall + (size_t)NR * ZD;

  dim3 blk(256);
  prep<<<2960, blk, 0, stream>>>(s, sp, a1h, Sb, SPb, aidx,
                                 pW0, pW0t, pW1, pW1t, pW2, pW2t,
                                 gW0, gW0t, gW1, gW1t, gW2, gW2t,
                                 (float*)d_out);

  gemm_lds<true, true, false, 256><<<dim3(32, 4, 2), blk, 0, stream>>>(
      Sb, SPb, pW0t, gW0t, pb0, gb0, H1, H1g, nullptr, 512, aidx, gW0);
  gemm_lds<true, false, false, 512><<<dim3(32, 4, 2), blk, 0, stream>>>(
      H1, H1g, pW1t, gW1t, pb1, gb1, H2, H2g, nullptr, 512, nullptr, nullptr);
  gemm_lds<false, false, true, 512><<<dim3(32, 1, 2), blk, 0, stream>>>(
      H2, H2g, pW2t, gW2t, pb2, gb2, Zb, Zpb, sqp2, 128, nullptr, nullptr);

  logits_fm<<<dim3(NR / 128, NJR), blk, 0, stream>>>(Zb, Zpb, sqp2, wm, wsm, wdg);
  finalize<<<NR / 256, blk, 0, stream>>>(wm, wsm, wdg, (float*)d_out);
}

// Round 7
// 54.469 us; speedup vs baseline: 6.9410x; 1.0355x over previous
//
#include <hip/hip_runtime.h>
#include <math.h>

#define NR 4096
#define ZD 128
#define HD 512
#define NJR 32
#define INV_T 10.0f

typedef __attribute__((ext_vector_type(8))) short bf16x8;
typedef __attribute__((ext_vector_type(4))) short short4v;
typedef __attribute__((ext_vector_type(4))) float f32x4;

typedef const unsigned int __attribute__((address_space(1)))* gas_t;
typedef unsigned int __attribute__((address_space(3)))* las_t;

__device__ __forceinline__ unsigned short f2bf(float f) {
  union { float f; unsigned u; } v; v.f = f;
  unsigned r = v.u + 0x7fff + ((v.u >> 16) & 1);
  return (unsigned short)(r >> 16);
}
__device__ __forceinline__ float bf2f(unsigned short b) {
  union { unsigned u; float f; } v; v.u = ((unsigned)b) << 16;
  return v.f;
}

// ======== fragment-major layout ========
// matrix [M][K]: fragment (rf=r>>4, ks=c>>5) = 1024B slot at (rf*(K>>5)+ks)*1024.
// lane l holds bf16x8 at lane*16: row = rf*16+(l&15), cols ks*32 + (l>>4)*4 + {0..3, 16..19}.

// ---------------------------------------------------------------- prep (unchanged)
__global__ __launch_bounds__(256) void prep(
    const float* __restrict__ s, const float* __restrict__ sp,
    const float* __restrict__ a1h,
    unsigned short* __restrict__ Sb, unsigned short* __restrict__ SPb,
    int* __restrict__ aidx,
    const float* __restrict__ pW0, unsigned short* __restrict__ pW0t,
    const float* __restrict__ pW1, unsigned short* __restrict__ pW1t,
    const float* __restrict__ pW2, unsigned short* __restrict__ pW2t,
    const float* __restrict__ gW0, unsigned short* __restrict__ gW0t,
    const float* __restrict__ gW1, unsigned short* __restrict__ gW1t,
    const float* __restrict__ gW2, unsigned short* __restrict__ gW2t,
    float* __restrict__ out) {
  int b = blockIdx.x, tid = threadIdx.x;
  if (b < 16) {
    int r = b * 256 + tid;
    int a = 0;
#pragma unroll
    for (int j = 0; j < 4; ++j) if (a1h[(size_t)r * 4 + j] > 0.5f) a = j;
    aidx[r] = a;
    if (b == 0 && tid == 0) out[0] = 0.f;
    return;
  }
  const int idx8 = tid & 127;
  const int h = idx8 & 1, p = idx8 >> 1, hi = p >> 4, l15 = p & 15;
  if (b < 2064) {
    const float* src = (b < 1040) ? s : sp;
    unsigned short* dst = (b < 1040) ? Sb : SPb;
    int lb = (b < 1040) ? b - 16 : b - 1040;
    int s0 = lb * 2 + (tid >> 7);
    int rf = s0 >> 3, ks = s0 & 7;
    int row = rf * 16 + l15, c0 = ks * 32 + hi * 4 + h * 16;
    float4 v = *(const float4*)&src[(size_t)row * 256 + c0];
    short4v o = { (short)f2bf(v.x), (short)f2bf(v.y), (short)f2bf(v.z), (short)f2bf(v.w) };
    *(short4v*)((char*)dst + (size_t)s0 * 1024 + idx8 * 8) = o;
    return;
  }
  int local = b - 2064;
  const float* W; unsigned short* Wt; int N, ksh;
  if (local < 128)      { W = pW0; Wt = pW0t; N = 512; ksh = 3; }
  else if (local < 384) { W = pW1; Wt = pW1t; N = 512; ksh = 4; local -= 128; }
  else if (local < 448) { W = pW2; Wt = pW2t; N = 128; ksh = 4; local -= 384; }
  else if (local < 576) { W = gW0; Wt = gW0t; N = 512; ksh = 3; local -= 448; }
  else if (local < 832) { W = gW1; Wt = gW1t; N = 512; ksh = 4; local -= 576; }
  else                  { W = gW2; Wt = gW2t; N = 128; ksh = 4; local -= 832; }
  int s0 = local * 2 + (tid >> 7);
  int rf = s0 >> ksh, ks = s0 & ((1 << ksh) - 1);
  int n = rf * 16 + l15, k0 = ks * 32 + hi * 4 + h * 16;
  short4v o = { (short)f2bf(W[(size_t)(k0 + 0) * N + n]),
                (short)f2bf(W[(size_t)(k0 + 1) * N + n]),
                (short)f2bf(W[(size_t)(k0 + 2) * N + n]),
                (short)f2bf(W[(size_t)(k0 + 3) * N + n]) };
  *(short4v*)((char*)Wt + (size_t)s0 * 1024 + idx8 * 8) = o;
}

// ---------------------------------------------------------------- triple-buffered GEMM
// BM x 64 block tile, BK=64, 4 waves (2x2). 3-deep global_load_lds pipeline,
// counted vmcnt, raw barriers. Frag-major in/out.
template <int BM, int K, bool RELU, bool GB, bool SQ>
__global__ __launch_bounds__(256) void gemm_p3(
    const unsigned short* __restrict__ A0, const unsigned short* __restrict__ A1,
    const unsigned short* __restrict__ W0, const unsigned short* __restrict__ W1,
    const float* __restrict__ b0, const float* __restrict__ b1,
    unsigned short* __restrict__ C0, unsigned short* __restrict__ C1,
    float* __restrict__ sqp2, int N,
    const int* __restrict__ aidx, const float* __restrict__ gW0f) {
  constexpr int KS = K >> 5;
  constexpr int NSTEP = K >> 6;
  constexpr int ABYTES = BM * 128;     // BM x 64 bf16
  constexpr int BBYTES = 8192;         // 64 x 64 bf16
  constexpr int NA = BM >> 5;          // A slots staged per wave per step
  constexpr int WM_FR = BM >> 5;       // row-fragments per wave
  constexpr int V = NA + 2;            // loads per wave per step
  __shared__ char lds[3 * (ABYTES + BBYTES)];
  char* AsB = lds;
  char* BsB = lds + 3 * ABYTES;

  const int tid = threadIdx.x, lane = tid & 63, w = tid >> 6;
  const int wm = w >> 1, wn = w & 1;
  const int z = blockIdx.z;
  const char* Ab = (const char*)(z ? A1 : A0);
  const char* Wb = (const char*)(z ? W1 : W0);
  const float* bias = z ? b1 : b0;
  char* Cb = (char*)(z ? C1 : C0);
  const int bm = blockIdx.x * BM, bn = blockIdx.y * 64;
  const int lane16 = lane * 16;

  auto stage = [&](int buf, int st) {
#pragma unroll
    for (int u = 0; u < NA; ++u) {
      const int sl = w * NA + u;
      const char* src = Ab + ((size_t)((bm >> 4) + (sl >> 1)) * KS + st * 2 + (sl & 1)) * 1024 + lane16;
      __builtin_amdgcn_global_load_lds((gas_t)src, (las_t)(AsB + buf * ABYTES + sl * 1024), 16, 0, 0);
    }
#pragma unroll
    for (int u = 0; u < 2; ++u) {
      const int sl = w * 2 + u;
      const char* src = Wb + ((size_t)((bn >> 4) + (sl >> 1)) * KS + st * 2 + (sl & 1)) * 1024 + lane16;
      __builtin_amdgcn_global_load_lds((gas_t)src, (las_t)(BsB + buf * BBYTES + sl * 1024), 16, 0, 0);
    }
  };

  f32x4 acc[WM_FR][2] = {};
  stage(0, 0);
  stage(1, 1);
#pragma unroll
  for (int st = 0; st < NSTEP; ++st) {
    const int buf = st % 3;
    if (st + 2 < NSTEP) {
      stage((st + 2) % 3, st + 2);
      if constexpr (V == 6) asm volatile("s_waitcnt vmcnt(12)" ::: "memory");
      else                  asm volatile("s_waitcnt vmcnt(8)" ::: "memory");
    } else if (st + 1 < NSTEP) {
      if constexpr (V == 6) asm volatile("s_waitcnt vmcnt(6)" ::: "memory");
      else                  asm volatile("s_waitcnt vmcnt(4)" ::: "memory");
    } else {
      asm volatile("s_waitcnt vmcnt(0)" ::: "memory");
    }
    __builtin_amdgcn_s_barrier();
#pragma unroll
    for (int kss = 0; kss < 2; ++kss) {
      bf16x8 af[WM_FR], bfv[2];
#pragma unroll
      for (int i = 0; i < WM_FR; ++i)
        af[i] = *(const bf16x8*)(AsB + buf * ABYTES + ((wm * WM_FR + i) * 2 + kss) * 1024 + lane16);
#pragma unroll
      for (int j = 0; j < 2; ++j)
        bfv[j] = *(const bf16x8*)(BsB + buf * BBYTES + ((wn * 2 + j) * 2 + kss) * 1024 + lane16);
#pragma unroll
      for (int i = 0; i < WM_FR; ++i)
#pragma unroll
        for (int j = 0; j < 2; ++j)
          acc[i][j] = __builtin_amdgcn_mfma_f32_16x16x32_bf16(bfv[j], af[i], acc[i][j], 0, 0, 0);
    }
    __builtin_amdgcn_s_barrier();
  }

  // epilogue: lane&15 = out-row, hi*4+e = out-col within 16-col frag
  const int l15 = lane & 15, hi = lane >> 4;
  const int NS = N >> 5;
  const int row0 = bm + wm * (BM / 2);
  const int col0 = bn + wn * 32;
  float sq[WM_FR];
  int ar[WM_FR];
#pragma unroll
  for (int i = 0; i < WM_FR; ++i) { sq[i] = 0.f; ar[i] = 0; }
  if (GB && z == 1) {
#pragma unroll
    for (int i = 0; i < WM_FR; ++i) ar[i] = aidx[row0 + i * 16 + l15];
  }
  float4 bi0 = *(const float4*)&bias[col0 + hi * 4];
  float4 bi1 = *(const float4*)&bias[col0 + 16 + hi * 4];
#pragma unroll
  for (int i = 0; i < WM_FR; ++i) {
    const int rfC = (row0 >> 4) + i;
    float v[8] = { acc[i][0][0] + bi0.x, acc[i][0][1] + bi0.y,
                   acc[i][0][2] + bi0.z, acc[i][0][3] + bi0.w,
                   acc[i][1][0] + bi1.x, acc[i][1][1] + bi1.y,
                   acc[i][1][2] + bi1.z, acc[i][1][3] + bi1.w };
    if (GB && z == 1) {
      float4 g0 = *(const float4*)&gW0f[(size_t)(256 + ar[i]) * N + col0 + hi * 4];
      float4 g1 = *(const float4*)&gW0f[(size_t)(256 + ar[i]) * N + col0 + 16 + hi * 4];
      v[0] += g0.x; v[1] += g0.y; v[2] += g0.z; v[3] += g0.w;
      v[4] += g1.x; v[5] += g1.y; v[6] += g1.z; v[7] += g1.w;
    }
    bf16x8 r;
#pragma unroll
    for (int t = 0; t < 8; ++t) {
      float vv = RELU ? fmaxf(v[t], 0.f) : v[t];
      unsigned short cv = f2bf(vv);
      r[t] = (short)cv;
      if (SQ) { float vb = bf2f(cv); sq[i] += vb * vb; }
    }
    *(bf16x8*)(Cb + (size_t)(rfC * NS + (col0 >> 5)) * 1024 + lane16) = r;
  }
  if (SQ && z == 1) {
#pragma unroll
    for (int i = 0; i < WM_FR; ++i) {
      float t = sq[i];
      t += __shfl_xor(t, 16, 64);
      t += __shfl_xor(t, 32, 64);
      if (lane < 16) sqp2[(size_t)(col0 >> 5) * NR + row0 + i * 16 + lane] = t;
    }
  }
}

// ---------------------------------------------------------------- logits (no LDS, swapped operands)
// grid (NR/128, NJR). Wave: 32 Z-rows x 128 Zp-cols; B-frags direct from L2.
__global__ __launch_bounds__(256) void logits_fm(
    const unsigned short* __restrict__ Zb, const unsigned short* __restrict__ Zpb,
    const float* __restrict__ sqp2, float* __restrict__ wm_,
    float* __restrict__ wsum, float* __restrict__ wdiag) {
  const int tid = threadIdx.x, lane = tid & 63, w = tid >> 6;
  const int l15 = lane & 15, hi = lane >> 4;
  const int i0 = blockIdx.x * 128, jr = blockIdx.y;
  const int row32 = i0 + w * 32;
  const int jbase = jr * 128;
  const int lane16 = lane * 16;
  const char* Zc = (const char*)Zb;
  const char* Pc = (const char*)Zpb;

  bf16x8 afr[2][4];
#pragma unroll
  for (int rf = 0; rf < 2; ++rf)
#pragma unroll
    for (int ks = 0; ks < 4; ++ks)
      afr[rf][ks] = *(const bf16x8*)(Zc + (size_t)(((row32 >> 4) + rf) * 4 + ks) * 1024 + lane16);

  f32x4 acc[2][8] = {};
#pragma unroll
  for (int jf = 0; jf < 8; ++jf) {
    const size_t js = (size_t)((jbase >> 4) + jf) * 4;
#pragma unroll
    for (int ks = 0; ks < 4; ++ks) {
      bf16x8 bfv = *(const bf16x8*)(Pc + (js + ks) * 1024 + lane16);
      acc[0][jf] = __builtin_amdgcn_mfma_f32_16x16x32_bf16(bfv, afr[0][ks], acc[0][jf], 0, 0, 0);
      acc[1][jf] = __builtin_amdgcn_mfma_f32_16x16x32_bf16(bfv, afr[1][ks], acc[1][jf], 0, 0, 0);
    }
  }

#pragma unroll
  for (int rf = 0; rf < 2; ++rf) {
    const int grow = row32 + rf * 16 + l15;
    float mx = -INFINITY, dd = 0.f;
    bool hasd = false;
#pragma unroll
    for (int jf = 0; jf < 8; ++jf) {
      const int cb = jbase + jf * 16 + hi * 4;
      float4 q0 = *(const float4*)&sqp2[cb];
      float4 q1 = *(const float4*)&sqp2[NR + cb];
      float4 q2 = *(const float4*)&sqp2[2 * NR + cb];
      float4 q3 = *(const float4*)&sqp2[3 * NR + cb];
      float sp[4] = { q0.x + q1.x + q2.x + q3.x, q0.y + q1.y + q2.y + q3.y,
                      q0.z + q1.z + q2.z + q3.z, q0.w + q1.w + q2.w + q3.w };
#pragma unroll
      for (int e = 0; e < 4; ++e) {
        float lv = (2.f * acc[rf][jf][e] - sp[e]) * INV_T;
        acc[rf][jf][e] = lv;
        mx = fmaxf(mx, lv);
        if (cb + e == grow) { dd = lv; hasd = true; }
      }
    }
    mx = fmaxf(mx, __shfl_xor(mx, 16, 64));
    mx = fmaxf(mx, __shfl_xor(mx, 32, 64));
    float sum = 0.f;
#pragma unroll
    for (int jf = 0; jf < 8; ++jf)
#pragma unroll
      for (int e = 0; e < 4; ++e) sum += __expf(acc[rf][jf][e] - mx);
    sum += __shfl_xor(sum, 16, 64);
    sum += __shfl_xor(sum, 32, 64);
    if (hi == 0) {
      wm_[(size_t)jr * NR + grow] = mx;
      wsum[(size_t)jr * NR + grow] = sum;
    }
    if (hasd) wdiag[grow] = dd;
  }
}

// ---------------------------------------------------------------- final combine
__global__ __launch_bounds__(256) void finalize(const float* __restrict__ wm,
    const float* __restrict__ wsum, const float* __restrict__ wdiag,
    float* __restrict__ out) {
  int r = blockIdx.x * 256 + threadIdx.x;
  float mm = wm[r];
  float ss = wsum[r];
#pragma unroll
  for (int p = 1; p < NJR; ++p) {
    float mo = wm[(size_t)p * NR + r];
    float so = wsum[(size_t)p * NR + r];
    float mn = fmaxf(mm, mo);
    ss = ss * __expf(mm - mn) + so * __expf(mo - mn);
    mm = mn;
  }
  float loss_r = mm + logf(ss) - wdiag[r];
  float v = loss_r;
#pragma unroll
  for (int off = 32; off; off >>= 1) v += __shfl_xor(v, off, 64);
  __shared__ float partial[4];
  if ((threadIdx.x & 63) == 0) partial[threadIdx.x >> 6] = v;
  __syncthreads();
  if (threadIdx.x == 0)
    atomicAdd(out, (partial[0] + partial[1] + partial[2] + partial[3]) * (1.0f / (float)NR));
}

// ---------------------------------------------------------------- launch
extern "C" void kernel_launch(void* const* d_in, const int* in_sizes, int n_in,
                              void* d_out, int out_size, void* d_ws, size_t ws_size,
                              hipStream_t stream) {
  const float* s   = (const float*)d_in[0];
  const float* sp  = (const float*)d_in[1];
  const float* a1h = (const float*)d_in[2];
  const float* pW0 = (const float*)d_in[3];
  const float* pb0 = (const float*)d_in[4];
  const float* pW1 = (const float*)d_in[5];
  const float* pb1 = (const float*)d_in[6];
  const float* pW2 = (const float*)d_in[7];
  const float* pb2 = (const float*)d_in[8];
  const float* gW0 = (const float*)d_in[9];
  const float* gb0 = (const float*)d_in[10];
  const float* gW1 = (const float*)d_in[11];
  const float* gb1 = (const float*)d_in[12];
  const float* gW2 = (const float*)d_in[13];
  const float* gb2 = (const float*)d_in[14];

  char* p = (char*)d_ws;
  unsigned short* Sb   = (unsigned short*)p; p += (size_t)NR * 256 * 2;
  unsigned short* SPb  = (unsigned short*)p; p += (size_t)NR * 256 * 2;
  unsigned short* H1   = (unsigned short*)p; p += (size_t)2 * NR * HD * 2;
  unsigned short* H2   = (unsigned short*)p; p += (size_t)2 * NR * HD * 2;
  unsigned short* Zall = (unsigned short*)p; p += (size_t)2 * NR * ZD * 2;
  unsigned short* pW0t = (unsigned short*)p; p += (size_t)256 * 512 * 2;
  unsigned short* pW1t = (unsigned short*)p; p += (size_t)512 * 512 * 2;
  unsigned short* pW2t = (unsigned short*)p; p += (size_t)512 * 128 * 2;
  unsigned short* gW0t = (unsigned short*)p; p += (size_t)256 * 512 * 2;
  unsigned short* gW1t = (unsigned short*)p; p += (size_t)512 * 512 * 2;
  unsigned short* gW2t = (unsigned short*)p; p += (size_t)512 * 128 * 2;
  float* sqp2 = (float*)p; p += (size_t)4 * NR * 4;
  float* wm   = (float*)p; p += (size_t)NJR * NR * 4;
  float* wsm  = (float*)p; p += (size_t)NJR * NR * 4;
  float* wdg  = (float*)p; p += (size_t)NR * 4;
  int*   aidx = (int*)p;  p += (size_t)NR * 4;

  unsigned short* H1g = H1 + (size_t)NR * HD;
  unsigned short* H2g = H2 + (size_t)NR * HD;
  unsigned short* Zb  = Zall;
  unsigned short* Zpb = Zall + (size_t)NR * ZD;

  dim3 blk(256);
  prep<<<2960, blk, 0, stream>>>(s, sp, a1h, Sb, SPb, aidx,
                                 pW0, pW0t, pW1, pW1t, pW2, pW2t,
                                 gW0, gW0t, gW1, gW1t, gW2, gW2t,
                                 (float*)d_out);

  gemm_p3<128, 256, true, true, false><<<dim3(32, 8, 2), blk, 0, stream>>>(
      Sb, SPb, pW0t, gW0t, pb0, gb0, H1, H1g, nullptr, 512, aidx, gW0);
  gemm_p3<128, 512, true, false, false><<<dim3(32, 8, 2), blk, 0, stream>>>(
      H1, H1g, pW1t, gW1t, pb1, gb1, H2, H2g, nullptr, 512, nullptr, nullptr);
  gemm_p3<64, 512, false, false, true><<<dim3(64, 2, 2), blk, 0, stream>>>(
      H2, H2g, pW2t, gW2t, pb2, gb2, Zb, Zpb, sqp2, 128, nullptr, nullptr);

  logits_fm<<<dim3(NR / 128, NJR), blk, 0, stream>>>(Zb, Zpb, sqp2, wm, wsm, wdg);
  finalize<<<NR / 256, blk, 0, stream>>>(wm, wsm, wdg, (float*)d_out);
}